// Round 6
// baseline (272.419 us; speedup 1.0000x reference)
//
#include <hip/hip_runtime.h>
#include <hip/hip_bf16.h>

#define TPB 256
#define SH 6
#define BW 64  // nodes per bucket = 1<<SH; NBUK must be <= 1024 (N <= 65536)

typedef unsigned short u16;
typedef unsigned char u8;
typedef __attribute__((ext_vector_type(8))) __bf16 bf16x8;  // MFMA A/B frag (4 VGPRs)
typedef __attribute__((ext_vector_type(4))) float f32x4;    // MFMA C/D frag

// bf16 helpers (LDS staging for MFMA stays bf16; payload is fp8).
__device__ __forceinline__ u16 f_to_bf(float f) {
    unsigned u = __float_as_uint(f);
    return (u16)((u + 0x7fff + ((u >> 16) & 1)) >> 16);  // RNE
}
__device__ __forceinline__ unsigned pkbf(float a, float b) {
    return (unsigned)f_to_bf(a) | ((unsigned)f_to_bf(b) << 16);
}
__device__ __forceinline__ void facc(float4& a, float4 v) {
    a.x += v.x; a.y += v.y; a.z += v.z; a.w += v.w;
}

// ---- fp8 e4m3 payload (OCP, HW cvt). fp32 accumulate. ----
__device__ __forceinline__ u8 f_to_fp8(float f) {
    return (u8)(__builtin_amdgcn_cvt_pk_fp8_f32(f, f, 0, false) & 0xff);
}
__device__ __forceinline__ void dec16(uint4 d, float* __restrict__ f) {
    auto w = __builtin_amdgcn_cvt_pk_f32_fp8(d.x, false); f[0] = w[0]; f[1] = w[1];
    w = __builtin_amdgcn_cvt_pk_f32_fp8(d.x, true);  f[2] = w[0];  f[3] = w[1];
    w = __builtin_amdgcn_cvt_pk_f32_fp8(d.y, false); f[4] = w[0];  f[5] = w[1];
    w = __builtin_amdgcn_cvt_pk_f32_fp8(d.y, true);  f[6] = w[0];  f[7] = w[1];
    w = __builtin_amdgcn_cvt_pk_f32_fp8(d.z, false); f[8] = w[0];  f[9] = w[1];
    w = __builtin_amdgcn_cvt_pk_f32_fp8(d.z, true);  f[10] = w[0]; f[11] = w[1];
    w = __builtin_amdgcn_cvt_pk_f32_fp8(d.w, false); f[12] = w[0]; f[13] = w[1];
    w = __builtin_amdgcn_cvt_pk_f32_fp8(d.w, true);  f[14] = w[0]; f[15] = w[1];
}
__device__ __forceinline__ void acc16_add(float* __restrict__ a, uint4 d) {
    float t[16];
    dec16(d, t);
#pragma unroll
    for (int i = 0; i < 16; i++) a[i] += t[i];
}
__device__ __forceinline__ void red16(float* __restrict__ a, int mask) {
#pragma unroll
    for (int i = 0; i < 16; i++) a[i] += __shfl_xor(a[i], mask, 16);
}

// XCD-aware block swizzle (4 XCDs per graph): blk&7 = XCD on MI355X.
__device__ __forceinline__ bool swz_block(int nblk, int& g, int& bx) {
    int blk = blockIdx.x;
    int j = blk & 7;
    g = j >> 2;
    bx = (blk >> 3) * 4 + (j & 3);
    return bx < nblk;
}

// ---- fp8 gather: EPG edges x CHUNKS 16B-chunks per lane group ----
// Per batch of 4*EPG edges: 4 col loads + 4 uint4 gathers (8 VMEM wave-instrs).
// Requests/edge = CHUNKS (half of bf16), and same-row chunk lanes are same-line
// (TA-mergeable). acc[16] fp32 per lane.
template <int CB, int EPG>
__device__ __forceinline__ void gather_fp8(const u8* __restrict__ HW,
                                           const int* __restrict__ col,
                                           int e, int c16, int ps, int pe,
                                           float* __restrict__ acc) {
    int p = ps;
    for (; p + 4 * EPG <= pe; p += 4 * EPG) {
        int j[4];
        uint4 d[4];
#pragma unroll
        for (int r = 0; r < 4; r++) j[r] = col[p + EPG * r + e];
#pragma unroll
        for (int r = 0; r < 4; r++) d[r] = *(const uint4*)&HW[(size_t)j[r] * CB + c16 * 16];
#pragma unroll
        for (int r = 0; r < 4; r++) acc16_add(acc, d[r]);
    }
    for (; p + EPG <= pe; p += EPG) {
        int j = col[p + e];
        acc16_add(acc, *(const uint4*)&HW[(size_t)j * CB + c16 * 16]);
    }
    if (p + e < pe) {
        int j = col[p + e];
        acc16_add(acc, *(const uint4*)&HW[(size_t)j * CB + c16 * 16]);
    }
}

// ---------------- capacity-bucket CSR build (no count/scan passes) ----------------

__global__ void bucket_scatter_kernel(const int* __restrict__ e0, const int* __restrict__ e1,
                                      int E, int* __restrict__ bcur,
                                      int* __restrict__ ebuf0, int* __restrict__ ebuf1,
                                      int nbuk, int cap) {
    int g = blockIdx.y;
    const int* src = g ? e1 : e0;
    const int* dst = src + E;
    int* ebuf = g ? ebuf1 : ebuf0;
    int* bu = bcur + g * 1024;
    __shared__ int hist[1024];
    for (int t = threadIdx.x; t < 1024; t += TPB) hist[t] = 0;
    __syncthreads();
    int base = blockIdx.x * 4096;
    int pk[16], bk[16], rk[16];
#pragma unroll
    for (int k = 0; k < 16; k++) {
        int e = base + k * TPB + (int)threadIdx.x;
        bk[k] = -1;
        if (e < E) {
            int s = src[e], d = dst[e];
            int b = d >> SH;
            bk[k] = b;
            pk[k] = (s << SH) | (d & (BW - 1));
            rk[k] = atomicAdd(&hist[b], 1);
        }
    }
    __syncthreads();
    for (int t = threadIdx.x; t < nbuk; t += TPB) {
        int h = hist[t];
        hist[t] = h ? atomicAdd(&bu[t], h) : 0;
    }
    __syncthreads();
#pragma unroll
    for (int k = 0; k < 16; k++)
        if (bk[k] >= 0) {
            int pos = hist[bk[k]] + rk[k];
            if (pos < cap) ebuf[(size_t)bk[k] * cap + pos] = pk[k];
        }
}

// Per-bucket: histogram -> local scan -> soff/eoff/dinv -> fill col (bucket-local).
__global__ void bucket_csr_kernel(const int* __restrict__ ebuf0, const int* __restrict__ ebuf1,
                                  const int* __restrict__ bcur, int n, int cap,
                                  int* __restrict__ soff0, int* __restrict__ soff1,
                                  int* __restrict__ eoff0, int* __restrict__ eoff1,
                                  float* __restrict__ dinv0, float* __restrict__ dinv1,
                                  int* __restrict__ col0, int* __restrict__ col1) {
    int g = blockIdx.y;
    int b = blockIdx.x;
    const int* ebuf = g ? ebuf1 : ebuf0;
    int* soff = g ? soff1 : soff0;
    int* eoff = g ? eoff1 : eoff0;
    float* dinv = g ? dinv1 : dinv0;
    int* col = g ? col1 : col0;
    __shared__ int h[BW], nb[BW], nrank[BW];
    int tid = threadIdx.x;
    if (tid < BW) h[tid] = 0;
    __syncthreads();
    int s = b * cap;
    int cnt = min(bcur[g * 1024 + b], cap);
    int e = s + cnt;
    for (int i = s + tid; i < e; i += TPB)
        atomicAdd(&h[ebuf[i] & (BW - 1)], 1);
    __syncthreads();
    if (tid < BW) {
        int v = h[tid];
        int x = v;
        for (int d = 1; d < BW; d <<= 1) {
            int u = __shfl_up(x, d, 64);
            if (tid >= d) x += u;
        }
        int base = s + x - v;  // exclusive prefix within bucket region
        nb[tid] = base;
        nrank[tid] = 0;
        int node = b * BW + tid;
        if (node < n) {
            soff[node] = base;
            eoff[node] = base + v;
            dinv[node] = rsqrtf((float)v + 1.0f);
        }
    }
    __syncthreads();
    for (int i = s + tid; i < e; i += TPB) {
        int p = ebuf[i];
        int lo = p & (BW - 1);
        int r = atomicAdd(&nrank[lo], 1);
        col[nb[lo] + r] = p >> SH;
    }
}

// ---------------- dense matmul via MFMA: Y = fp8( dinv[n] * (X @ W) ) ----------

template <int CIN, int COUT>
__global__ void matmul_kernel(const float* __restrict__ X0, const float* __restrict__ X1,
                              const float* __restrict__ W,
                              const float* __restrict__ dinv0, const float* __restrict__ dinv1,
                              u8* __restrict__ Y0, u8* __restrict__ Y1, int n) {
    constexpr int CINP = CIN + 8;
    constexpr int NT = COUT / 16;
    constexpr int KT = CIN / 32;
    __shared__ u16 Xs[64 * CINP];
    __shared__ u16 Wt[COUT * CINP];

    int g = blockIdx.y;
    const float* X = g ? X1 : X0;
    const float* dinv = g ? dinv1 : dinv0;
    u8* Y = g ? Y1 : Y0;
    int nb0 = blockIdx.x * 64;

    for (int i = threadIdx.x; i < 64 * (CIN / 4); i += TPB) {
        int nn = i / (CIN / 4), kc = i % (CIN / 4);
        float4 v = make_float4(0.f, 0.f, 0.f, 0.f);
        if (nb0 + nn < n) v = *(const float4*)&X[(size_t)(nb0 + nn) * CIN + 4 * kc];
        ushort4 b;
        b.x = f_to_bf(v.x); b.y = f_to_bf(v.y); b.z = f_to_bf(v.z); b.w = f_to_bf(v.w);
        *(ushort4*)&Xs[nn * CINP + 4 * kc] = b;
    }
    for (int i = threadIdx.x; i < CIN * (COUT / 4); i += TPB) {
        int k = i / (COUT / 4), nc4 = i % (COUT / 4);
        float4 v = *(const float4*)&W[(size_t)k * COUT + 4 * nc4];
        Wt[(4 * nc4 + 0) * CINP + k] = f_to_bf(v.x);
        Wt[(4 * nc4 + 1) * CINP + k] = f_to_bf(v.y);
        Wt[(4 * nc4 + 2) * CINP + k] = f_to_bf(v.z);
        Wt[(4 * nc4 + 3) * CINP + k] = f_to_bf(v.w);
    }
    __syncthreads();

    int lane = threadIdx.x & 63;
    int w = threadIdx.x >> 6;
    int m = lane & 15;
    int quad = lane >> 4;

    f32x4 acc[NT];
#pragma unroll
    for (int t = 0; t < NT; t++) acc[t] = (f32x4){0.f, 0.f, 0.f, 0.f};
#pragma unroll
    for (int kt = 0; kt < KT; kt++) {
        int k0 = kt * 32 + quad * 8;
        bf16x8 a = *(const bf16x8*)&Xs[(w * 16 + m) * CINP + k0];
#pragma unroll
        for (int t = 0; t < NT; t++) {
            bf16x8 b = *(const bf16x8*)&Wt[(t * 16 + m) * CINP + k0];
            acc[t] = __builtin_amdgcn_mfma_f32_16x16x32_bf16(a, b, acc[t], 0, 0, 0);
        }
    }
#pragma unroll
    for (int r = 0; r < 4; r++) {
        int node = nb0 + w * 16 + quad * 4 + r;
        if (node < n) {
            float d = dinv[node];
#pragma unroll
            for (int t = 0; t < NT; t++)
                Y[(size_t)node * COUT + t * 16 + m] = f_to_fp8(acc[t][r] * d);
        }
    }
}

// ------- fused GCN agg (fp8 payload, EPG=4 gather) + MFMA next-layer matmul -------
// Block = 16 nodes (16 threads/node). Lane tiling: (e in [0,EPG)) x (c16 in
// [0,CHUNKS)) x SPLIT slices. Gather+relu -> bf16 H rows in LDS; MFMA epilogue
// computes Y = fp8(dinv * (H @ W2)).

template <int C, int COUT2>
__global__ __launch_bounds__(TPB, 2)
void agg_mm_kernel(const u8* __restrict__ HW0, const u8* __restrict__ HW1,
                   const int* __restrict__ soff0, const int* __restrict__ soff1,
                   const int* __restrict__ eoff0, const int* __restrict__ eoff1,
                   const int* __restrict__ col0, const int* __restrict__ col1,
                   const float* __restrict__ dinv0, const float* __restrict__ dinv1,
                   const float* __restrict__ bias, const float* __restrict__ W2,
                   u8* __restrict__ Y0, u8* __restrict__ Y1, int n, int nblk) {
    constexpr int CHUNKS = C / 16;   // 16B fp8 chunks per row
    constexpr int EPG = 4;           // edges in flight per group
    constexpr int GRP = EPG * CHUNKS;
    constexpr int SPLIT = 16 / GRP;  // edge-list slices per node
    constexpr int CP = C + 8;        // padded LDS row stride (u16), 16B-aligned rows
    constexpr int NT2 = COUT2 / 16;  // MFMA col-tiles
    constexpr int KT2 = C / 32;      // MFMA k-tiles
    __shared__ __align__(16) u16 HsB[16 * CP];
    __shared__ __align__(16) u16 WtB[COUT2 * CP];

    int g, bx;
    if (!swz_block(nblk, g, bx)) return;
    const u8* HW = g ? HW1 : HW0;
    const int* soff = g ? soff1 : soff0;
    const int* eoff = g ? eoff1 : eoff0;
    const int* col = g ? col1 : col0;
    const float* dinv = g ? dinv1 : dinv0;
    u8* Y = g ? Y1 : Y0;

    // stage W2 transposed (bf16) while gather loads are in flight
    for (int idx = threadIdx.x; idx < C * COUT2; idx += TPB) {
        int k = idx / COUT2, nc = idx % COUT2;
        WtB[nc * CP + k] = f_to_bf(W2[idx]);
    }

    int nl = threadIdx.x >> 4;
    int part = threadIdx.x & 15;
    int sp = part / GRP;
    int gl = part % GRP;
    int e = gl / CHUNKS;
    int c16 = gl % CHUNKS;
    int node = bx * 16 + nl;

    float acc[16], o16[16];
#pragma unroll
    for (int i = 0; i < 16; i++) { acc[i] = 0.f; o16[i] = 0.f; }

    if (node < n) {
        int s = soff[node], en = eoff[node];
        int len = en - s;
        int chunk = (len + SPLIT - 1) / SPLIT;
        int ps = s + sp * chunk;
        int pe = min(ps + chunk, en);
        gather_fp8<C, EPG>(HW, col, e, c16, ps, pe, acc);
#pragma unroll
        for (int m = CHUNKS; m < 16; m <<= 1) red16(acc, m);
        if (part < CHUNKS) {  // writer lane: holds channels [part*16, part*16+16)
            float di = dinv[node];
            float sv[16];
            dec16(*(const uint4*)&HW[(size_t)node * C + part * 16], sv);
#pragma unroll
            for (int i = 0; i < 16; i++)
                o16[i] = fmaxf(di * (acc[i] + sv[i]) + bias[part * 16 + i], 0.f);
        }
    }
    if (part < CHUNKS) {  // zeros for tail nodes
        uint4 h0, h1;
        h0.x = pkbf(o16[0], o16[1]);   h0.y = pkbf(o16[2], o16[3]);
        h0.z = pkbf(o16[4], o16[5]);   h0.w = pkbf(o16[6], o16[7]);
        h1.x = pkbf(o16[8], o16[9]);   h1.y = pkbf(o16[10], o16[11]);
        h1.z = pkbf(o16[12], o16[13]); h1.w = pkbf(o16[14], o16[15]);
        *(uint4*)&HsB[nl * CP + part * 16] = h0;
        *(uint4*)&HsB[nl * CP + part * 16 + 8] = h1;
    }
    __syncthreads();

    // MFMA epilogue: wave w computes 16 nodes x out-cols [w*16, w*16+16)
    int lane = threadIdx.x & 63;
    int w = threadIdx.x >> 6;
    if (w < NT2) {
        int m = lane & 15;
        int quad = lane >> 4;
        f32x4 ac = (f32x4){0.f, 0.f, 0.f, 0.f};
#pragma unroll
        for (int kt = 0; kt < KT2; kt++) {
            int k0 = kt * 32 + quad * 8;
            bf16x8 a = *(const bf16x8*)&HsB[m * CP + k0];
            bf16x8 b = *(const bf16x8*)&WtB[(w * 16 + m) * CP + k0];
            ac = __builtin_amdgcn_mfma_f32_16x16x32_bf16(a, b, ac, 0, 0, 0);
        }
        int base16 = bx * 16;
#pragma unroll
        for (int r = 0; r < 4; r++) {
            int onode = base16 + quad * 4 + r;
            if (onode < n)
                Y[(size_t)onode * COUT2 + w * 16 + m] = f_to_fp8(ac[r] * dinv[onode]);
        }
    }
}

// Layer-3 aggregation (C=16 fp8: ONE 16B request per edge) + bf16 H3 out +
// per-block colsum partials (NO atomics).
__global__ __launch_bounds__(TPB, 2)
void agg16_kernel(const u8* __restrict__ HW0, const u8* __restrict__ HW1,
                  const int* __restrict__ soff0, const int* __restrict__ soff1,
                  const int* __restrict__ eoff0, const int* __restrict__ eoff1,
                  const int* __restrict__ col0, const int* __restrict__ col1,
                  const float* __restrict__ dinv0, const float* __restrict__ dinv1,
                  const float* __restrict__ bias,
                  u16* __restrict__ out0, u16* __restrict__ out1,
                  float* __restrict__ pcol, int n, int nblk) {
    constexpr int EPG = 4;  // CHUNKS=1, GRP=4, SPLIT=4
    int g, bx;
    if (!swz_block(nblk, g, bx)) return;
    const u8* HW = g ? HW1 : HW0;
    const int* soff = g ? soff1 : soff0;
    const int* eoff = g ? eoff1 : eoff0;
    const int* col = g ? col1 : col0;
    const float* dinv = g ? dinv1 : dinv0;
    u16* outp = g ? out1 : out0;

    int nl = threadIdx.x >> 4;
    int part = threadIdx.x & 15;
    int sp = part >> 2;
    int e = part & 3;
    int node = bx * 16 + nl;

    float acc[16], o16[16];
#pragma unroll
    for (int i = 0; i < 16; i++) { acc[i] = 0.f; o16[i] = 0.f; }

    if (node < n) {
        int s = soff[node], en = eoff[node];
        int len = en - s;
        int chunk = (len + 3) >> 2;
        int ps = s + sp * chunk;
        int pe = min(ps + chunk, en);
        gather_fp8<16, EPG>(HW, col, e, 0, ps, pe, acc);
        red16(acc, 1);
        red16(acc, 2);
        red16(acc, 4);
        red16(acc, 8);
        if (part == 0) {
            float di = dinv[node];
            float sv[16];
            dec16(*(const uint4*)&HW[(size_t)node * 16], sv);
#pragma unroll
            for (int i = 0; i < 16; i++)
                o16[i] = di * (acc[i] + sv[i]) + bias[i];
        }
    }
    // hand channels 8..15 to lane part==1 (group-local shfl from lane 0)
    float t8[8];
#pragma unroll
    for (int i = 0; i < 8; i++) t8[i] = __shfl(o16[8 + i], 0, 16);
    float o8v[8];
#pragma unroll
    for (int i = 0; i < 8; i++) o8v[i] = (part == 0) ? o16[i] : t8[i];

    if (node < n && part < 2) {
        uint4 hv;
        hv.x = pkbf(o8v[0], o8v[1]); hv.y = pkbf(o8v[2], o8v[3]);
        hv.z = pkbf(o8v[4], o8v[5]); hv.w = pkbf(o8v[6], o8v[7]);
        *(uint4*)&outp[(size_t)node * 16 + part * 8] = hv;
    }
    // per-block colsum partial: lanes part<2 hold chunk (part*8..part*8+7)
    __shared__ float4 sa[TPB], sb[TPB];
    bool hold = (node < n) && (part < 2);
    sa[threadIdx.x] = hold ? make_float4(o8v[0], o8v[1], o8v[2], o8v[3])
                           : make_float4(0.f, 0.f, 0.f, 0.f);
    sb[threadIdx.x] = hold ? make_float4(o8v[4], o8v[5], o8v[6], o8v[7])
                           : make_float4(0.f, 0.f, 0.f, 0.f);
    __syncthreads();
    if (threadIdx.x < 64) {
        float4 a = sa[threadIdx.x], b = sb[threadIdx.x];
        facc(a, sa[threadIdx.x + 64]);  facc(b, sb[threadIdx.x + 64]);
        facc(a, sa[threadIdx.x + 128]); facc(b, sb[threadIdx.x + 128]);
        facc(a, sa[threadIdx.x + 192]); facc(b, sb[threadIdx.x + 192]);
        sa[threadIdx.x] = a; sb[threadIdx.x] = b;
    }
    __syncthreads();
    if (threadIdx.x < 16) {
        float4 a = sa[threadIdx.x], b = sb[threadIdx.x];
        facc(a, sa[threadIdx.x + 16]); facc(b, sb[threadIdx.x + 16]);
        facc(a, sa[threadIdx.x + 32]); facc(b, sb[threadIdx.x + 32]);
        facc(a, sa[threadIdx.x + 48]); facc(b, sb[threadIdx.x + 48]);
        sa[threadIdx.x] = a; sb[threadIdx.x] = b;
    }
    __syncthreads();
    if (threadIdx.x < 2) {
        float* dst = &pcol[((size_t)g * nblk + bx) * 16 + threadIdx.x * 8];
        *(float4*)&dst[0] = sa[threadIdx.x];
        *(float4*)&dst[4] = sb[threadIdx.x];
    }
}

// ---------------- cvec: coalesced reduce of pcol partials + tanh(mean @ Wa) ----------

__global__ void cvec_kernel(const float* __restrict__ pcol, int nb16, float n_inv,
                            const float* __restrict__ Wa, float* __restrict__ cvec) {
    int g = blockIdx.x;
    const float4* p4 = (const float4*)(pcol + (size_t)g * nb16 * 16);
    __shared__ float4 sd[TPB];
    __shared__ float cs[16];
    int c4 = threadIdx.x & 3;
    int row = threadIdx.x >> 2;
    float4 acc = make_float4(0.f, 0.f, 0.f, 0.f);
    for (int r = row; r < nb16; r += 64) facc(acc, p4[(size_t)r * 4 + c4]);
    sd[threadIdx.x] = acc;
    __syncthreads();
    if (threadIdx.x < 64) {
        float4 a = sd[threadIdx.x];
        facc(a, sd[threadIdx.x + 64]);
        facc(a, sd[threadIdx.x + 128]);
        facc(a, sd[threadIdx.x + 192]);
        sd[threadIdx.x] = a;
    }
    __syncthreads();
    if (threadIdx.x < 16) {
        float4 a = sd[threadIdx.x];
        facc(a, sd[threadIdx.x + 16]);
        facc(a, sd[threadIdx.x + 32]);
        facc(a, sd[threadIdx.x + 48]);
        sd[threadIdx.x] = a;
    }
    __syncthreads();
    if (threadIdx.x < 4) {
        float4 a = sd[threadIdx.x];
        facc(a, sd[threadIdx.x + 4]);
        facc(a, sd[threadIdx.x + 8]);
        facc(a, sd[threadIdx.x + 12]);
        cs[threadIdx.x * 4 + 0] = a.x * n_inv;
        cs[threadIdx.x * 4 + 1] = a.y * n_inv;
        cs[threadIdx.x * 4 + 2] = a.z * n_inv;
        cs[threadIdx.x * 4 + 3] = a.w * n_inv;
    }
    __syncthreads();
    if (threadIdx.x < 16) {
        float acc2 = 0.f;
#pragma unroll
        for (int i = 0; i < 16; i++) acc2 += cs[i] * Wa[i * 16 + threadIdx.x];
        cvec[g * 16 + threadIdx.x] = tanhf(acc2);
    }
}

// ---------------- attention pooling (bf16 H3, per-block partials) ----------------

__global__ void pool_kernel(const u16* __restrict__ H0, const u16* __restrict__ H1, int n,
                            const float* __restrict__ cvec, float* __restrict__ ppool) {
    int g = blockIdx.y;
    const u16* H = g ? H1 : H0;
    int c = threadIdx.x & 15;
    float cv = cvec[g * 16 + c];
    int w = (blockIdx.x * blockDim.x + threadIdx.x) / 16;
    int stride = (gridDim.x * blockDim.x) / 16;
    float acc = 0.f;
    for (int node = w; node < n; node += stride) {
        float x = __uint_as_float((unsigned)H[(size_t)node * 16 + c] << 16);
        float p = x * cv;
        p += __shfl_xor(p, 1, 16);
        p += __shfl_xor(p, 2, 16);
        p += __shfl_xor(p, 4, 16);
        p += __shfl_xor(p, 8, 16);
        float s = 1.f / (1.f + __expf(-p));
        acc += s * x;
    }
    __shared__ float sdata[TPB];
    sdata[threadIdx.x] = acc;
    __syncthreads();
    if (threadIdx.x < 16) {
        float s = 0.f;
        for (int t = threadIdx.x; t < TPB; t += 16) s += sdata[t];
        ppool[((size_t)g * gridDim.x + blockIdx.x) * 16 + threadIdx.x] = s;
    }
}

// ---------------- final: parallel reduce of pool partials + tensor-network scoring ----

__global__ void final_kernel(const float* __restrict__ ppool, int nbp,
                             const float* __restrict__ Wt, const float* __restrict__ Wb,
                             const float* __restrict__ bt, const float* __restrict__ Wfc,
                             const float* __restrict__ bfc, const float* __restrict__ Wsc,
                             const float* __restrict__ bsc, float* __restrict__ out) {
    __shared__ float4 sd4[TPB];
    __shared__ float rep[32], part[TPB], scores[16], tvec[16];
    int t = threadIdx.x;
    {
        const float4* p4 = (const float4*)ppool;
        int g = t >> 7;
        int r0 = (t >> 2) & 31;
        int c4 = t & 3;
        float4 acc = make_float4(0.f, 0.f, 0.f, 0.f);
        for (int r = r0; r < nbp; r += 32)
            facc(acc, p4[((size_t)g * nbp + r) * 4 + c4]);
        sd4[t] = acc;
        __syncthreads();
        for (int st = 16; st >= 1; st >>= 1) {
            if (r0 < st) facc(sd4[t], sd4[t + st * 4]);
            __syncthreads();
        }
        if (r0 == 0) {
            float4 a = sd4[t];
            rep[g * 16 + c4 * 4 + 0] = a.x;
            rep[g * 16 + c4 * 4 + 1] = a.y;
            rep[g * 16 + c4 * 4 + 2] = a.z;
            rep[g * 16 + c4 * 4 + 3] = a.w;
        }
        __syncthreads();
    }
    {
        int p = t >> 4, tt = t & 15;
        float b = 0.f;
#pragma unroll
        for (int q = 0; q < 16; q++)
            b += rep[q] * Wt[(q * 16 + p) * 16 + tt];
        part[t] = b * rep[16 + p];
    }
    __syncthreads();
    if (t < 16) {
        float bil = 0.f;
#pragma unroll
        for (int p = 0; p < 16; p++) bil += part[p * 16 + t];
        float blk = 0.f;
#pragma unroll
        for (int m = 0; m < 16; m++)
            blk += Wb[t * 32 + m] * rep[m] + Wb[t * 32 + 16 + m] * rep[16 + m];
        scores[t] = fmaxf(bil + blk + bt[t], 0.f);
    }
    __syncthreads();
    if (t < 16) {
        float acc = bfc[t];
#pragma unroll
        for (int k = 0; k < 16; k++) acc += scores[k] * Wfc[k * 16 + t];
        tvec[t] = tanhf(acc);
    }
    __syncthreads();
    if (t == 0) {
        float acc = bsc[0];
#pragma unroll
        for (int j = 0; j < 16; j++) acc += tvec[j] * Wsc[j];
        out[0] = 1.f / (1.f + __expf(-acc));
    }
}

// ---------------- launcher ----------------

extern "C" void kernel_launch(void* const* d_in, const int* in_sizes, int n_in,
                              void* d_out, int out_size, void* d_ws, size_t ws_size,
                              hipStream_t stream) {
    const float* X1 = (const float*)d_in[0];
    const float* X2 = (const float*)d_in[1];
    const int* edges1 = (const int*)d_in[2];
    const int* edges2 = (const int*)d_in[3];
    const float* W1 = (const float*)d_in[4];
    const float* b1 = (const float*)d_in[5];
    const float* W2 = (const float*)d_in[6];
    const float* b2 = (const float*)d_in[7];
    const float* W3 = (const float*)d_in[8];
    const float* b3 = (const float*)d_in[9];
    const float* Wa = (const float*)d_in[10];
    const float* Wt = (const float*)d_in[11];
    const float* Wb = (const float*)d_in[12];
    const float* bt = (const float*)d_in[13];
    const float* Wfc = (const float*)d_in[14];
    const float* bfc = (const float*)d_in[15];
    const float* Wsc = (const float*)d_in[16];
    const float* bsc = (const float*)d_in[17];
    float* out = (float*)d_out;

    const int N = in_sizes[0] / 96;
    const int E = in_sizes[2] / 2;
    const int NBUK = (N + BW - 1) / BW;  // buckets (must be <= 1024)
    int cap = ((2 * (E / NBUK)) + 255) & ~255;  // bucket capacity: 2x average, safe
    if (cap < 256) cap = 256;

    char* ws = (char*)d_ws;
    size_t o = 0;
    auto alloc = [&](size_t bytes) {
        void* p = ws + o;
        o += (bytes + 255) & ~(size_t)255;
        return p;
    };
    int* bcur = (int*)alloc((size_t)2 * 1024 * 4);
    int* soff0 = (int*)alloc((size_t)N * 4);
    int* soff1 = (int*)alloc((size_t)N * 4);
    int* eoff0 = (int*)alloc((size_t)N * 4);
    int* eoff1 = (int*)alloc((size_t)N * 4);
    int* col0 = (int*)alloc((size_t)NBUK * cap * 4);
    int* col1 = (int*)alloc((size_t)NBUK * cap * 4);
    int* ebuf0 = (int*)alloc((size_t)NBUK * cap * 4);
    int* ebuf1 = (int*)alloc((size_t)NBUK * cap * 4);
    float* dinv0 = (float*)alloc((size_t)N * 4);
    float* dinv1 = (float*)alloc((size_t)N * 4);
    u8* hwbA0 = (u8*)alloc((size_t)N * 64);  // layer-1 payload (fp8)
    u8* hwbA1 = (u8*)alloc((size_t)N * 64);
    u8* hwbB0 = (u8*)alloc((size_t)N * 32);  // layer-2 payload (fp8)
    u8* hwbB1 = (u8*)alloc((size_t)N * 32);
    u8* hwbC0 = (u8*)alloc((size_t)N * 16);  // layer-3 payload (fp8)
    u8* hwbC1 = (u8*)alloc((size_t)N * 16);
    u16* H30 = (u16*)alloc((size_t)N * 16 * 2);  // H3 bf16 (pool input)
    u16* H31 = (u16*)alloc((size_t)N * 16 * 2);

    const int gB2 = (E + 4095) / 4096;
    const int g16 = ((size_t)N * 16 + TPB - 1) / TPB;  // aggs: 16 threads/node
    const int gSwz = 8 * ((g16 + 3) / 4);              // 4-XCD-per-graph swizzled grid
    const int gMM = (N + 63) / 64;
    const int gPool = 256;

    float* pcol = (float*)alloc((size_t)2 * g16 * 16 * 4);
    float* cvecArr = (float*)alloc(32 * 4);
    float* ppool = (float*)alloc((size_t)2 * gPool * 16 * 4);

    hipMemsetAsync(bcur, 0, (size_t)2 * 1024 * 4, stream);

    // capacity-bucket CSR build: scatter -> per-bucket finalize (no count/scan passes)
    bucket_scatter_kernel<<<dim3(gB2, 2), TPB, 0, stream>>>(edges1, edges2, E, bcur,
                                                            ebuf0, ebuf1, NBUK, cap);
    bucket_csr_kernel<<<dim3(NBUK, 2), TPB, 0, stream>>>(ebuf0, ebuf1, bcur, N, cap,
                                                         soff0, soff1, eoff0, eoff1,
                                                         dinv0, dinv1, col0, col1);

    // layer 1 matmul (MFMA 96->64), fp8 output
    matmul_kernel<96, 64><<<dim3(gMM, 2), TPB, 0, stream>>>(X1, X2, W1, dinv0, dinv1,
                                                            hwbA0, hwbA1, N);
    // layer-1 agg + fused layer-2 MFMA matmul (64 -> H1 -> @W2 -> 32 fp8)
    agg_mm_kernel<64, 32><<<gSwz, TPB, 0, stream>>>(
        hwbA0, hwbA1, soff0, soff1, eoff0, eoff1, col0, col1, dinv0, dinv1, b1, W2,
        hwbB0, hwbB1, N, g16);
    // layer-2 agg + fused layer-3 MFMA matmul (32 -> H2 -> @W3 -> 16 fp8)
    agg_mm_kernel<32, 16><<<gSwz, TPB, 0, stream>>>(
        hwbB0, hwbB1, soff0, soff1, eoff0, eoff1, col0, col1, dinv0, dinv1, b2, W3,
        hwbC0, hwbC1, N, g16);
    // layer-3 agg (writes H3 bf16 + colsum partials)
    agg16_kernel<<<gSwz, TPB, 0, stream>>>(
        hwbC0, hwbC1, soff0, soff1, eoff0, eoff1, col0, col1, dinv0, dinv1, b3,
        H30, H31, pcol, N, g16);

    // attention pooling + scoring
    cvec_kernel<<<2, TPB, 0, stream>>>(pcol, g16, 1.0f / (float)N, Wa, cvecArr);
    pool_kernel<<<dim3(gPool, 2), TPB, 0, stream>>>(H30, H31, N, cvecArr, ppool);
    final_kernel<<<1, 256, 0, stream>>>(ppool, gPool, Wt, Wb, bt, Wfc, bfc, Wsc, bsc, out);
}

// Round 7
// 262.003 us; speedup vs baseline: 1.0398x; 1.0398x over previous
//
#include <hip/hip_runtime.h>
#include <hip/hip_bf16.h>

#define TPB 256
#define SH 6
#define BW 64  // nodes per bucket = 1<<SH; NBUK must be <= 1024 (N <= 65536)

typedef unsigned short u16;
typedef __attribute__((ext_vector_type(8))) __bf16 bf16x8;  // MFMA A/B frag (4 VGPRs)
typedef __attribute__((ext_vector_type(4))) float f32x4;    // MFMA C/D frag

// bf16 helpers: payload stored as bf16 (halves gather BW), accumulate in fp32.
__device__ __forceinline__ u16 f_to_bf(float f) {
    unsigned u = __float_as_uint(f);
    return (u16)((u + 0x7fff + ((u >> 16) & 1)) >> 16);  // RNE
}
__device__ __forceinline__ unsigned pkbf(float a, float b) {
    return (unsigned)f_to_bf(a) | ((unsigned)f_to_bf(b) << 16);
}
__device__ __forceinline__ void facc(float4& a, float4 v) {
    a.x += v.x; a.y += v.y; a.z += v.z; a.w += v.w;
}

// 16B bf16 chunk (8 channels) decode/accumulate
__device__ __forceinline__ void bacc8(float* __restrict__ a, uint4 d) {
    a[0] += __uint_as_float(d.x << 16);
    a[1] += __uint_as_float(d.x & 0xffff0000u);
    a[2] += __uint_as_float(d.y << 16);
    a[3] += __uint_as_float(d.y & 0xffff0000u);
    a[4] += __uint_as_float(d.z << 16);
    a[5] += __uint_as_float(d.z & 0xffff0000u);
    a[6] += __uint_as_float(d.w << 16);
    a[7] += __uint_as_float(d.w & 0xffff0000u);
}
__device__ __forceinline__ void bdec8(uint4 d, float* __restrict__ f) {
    f[0] = __uint_as_float(d.x << 16);
    f[1] = __uint_as_float(d.x & 0xffff0000u);
    f[2] = __uint_as_float(d.y << 16);
    f[3] = __uint_as_float(d.y & 0xffff0000u);
    f[4] = __uint_as_float(d.z << 16);
    f[5] = __uint_as_float(d.z & 0xffff0000u);
    f[6] = __uint_as_float(d.w << 16);
    f[7] = __uint_as_float(d.w & 0xffff0000u);
}
__device__ __forceinline__ void red8(float* __restrict__ a, int mask, int width) {
#pragma unroll
    for (int i = 0; i < 8; i++) a[i] += __shfl_xor(a[i], mask, width);
}
__device__ __forceinline__ uint4 pack8(const float* __restrict__ o) {
    uint4 h;
    h.x = pkbf(o[0], o[1]); h.y = pkbf(o[2], o[3]);
    h.z = pkbf(o[4], o[5]); h.w = pkbf(o[6], o[7]);
    return h;
}

// XCD-aware block swizzle (4 XCDs per graph): blk&7 = XCD on MI355X.
__device__ __forceinline__ bool swz_block(int nblk, int& g, int& bx) {
    int blk = blockIdx.x;
    int j = blk & 7;
    g = j >> 2;
    bx = (blk >> 3) * 4 + (j & 3);
    return bx < nblk;
}

// ---- 16B/lane paired-edge gather (EPG=2; round-5 proven config) ----
// Group of 2*CHUNKS lanes tiles (2 edges) x (C/8 16B-chunks). u16 col indices.
template <int C>
__device__ __forceinline__ void gather_sum16(const u16* __restrict__ HW,
                                             const u16* __restrict__ col,
                                             int e, int c8, int ps, int pe,
                                             float* __restrict__ acc) {
    int p = ps;
    for (; p + 8 <= pe; p += 8) {
        int j[4];
        uint4 d[4];
#pragma unroll
        for (int r = 0; r < 4; r++) j[r] = col[p + 2 * r + e];
#pragma unroll
        for (int r = 0; r < 4; r++) d[r] = *(const uint4*)&HW[(size_t)j[r] * C + c8 * 8];
#pragma unroll
        for (int r = 0; r < 4; r++) bacc8(acc, d[r]);
    }
    for (; p + 2 <= pe; p += 2) {
        int j = col[p + e];
        bacc8(acc, *(const uint4*)&HW[(size_t)j * C + c8 * 8]);
    }
    if (p < pe && e == 0) {
        int j = col[p];
        bacc8(acc, *(const uint4*)&HW[(size_t)j * C + c8 * 8]);
    }
}

// ---------------- capacity-bucket CSR build (no count/scan passes) ----------------

__global__ void bucket_scatter_kernel(const int* __restrict__ e0, const int* __restrict__ e1,
                                      int E, int* __restrict__ bcur,
                                      int* __restrict__ ebuf0, int* __restrict__ ebuf1,
                                      int nbuk, int cap) {
    int g = blockIdx.y;
    const int* src = g ? e1 : e0;
    const int* dst = src + E;
    int* ebuf = g ? ebuf1 : ebuf0;
    int* bu = bcur + g * 1024;
    __shared__ int hist[1024];
    for (int t = threadIdx.x; t < 1024; t += TPB) hist[t] = 0;
    __syncthreads();
    int base = blockIdx.x * 4096;
    int pk[16], bk[16], rk[16];
#pragma unroll
    for (int k = 0; k < 16; k++) {
        int e = base + k * TPB + (int)threadIdx.x;
        bk[k] = -1;
        if (e < E) {
            int s = src[e], d = dst[e];
            int b = d >> SH;
            bk[k] = b;
            pk[k] = (s << SH) | (d & (BW - 1));
            rk[k] = atomicAdd(&hist[b], 1);
        }
    }
    __syncthreads();
    for (int t = threadIdx.x; t < nbuk; t += TPB) {
        int h = hist[t];
        hist[t] = h ? atomicAdd(&bu[t], h) : 0;
    }
    __syncthreads();
#pragma unroll
    for (int k = 0; k < 16; k++)
        if (bk[k] >= 0) {
            int pos = hist[bk[k]] + rk[k];
            if (pos < cap) ebuf[(size_t)bk[k] * cap + pos] = pk[k];
        }
}

// Per-bucket: histogram -> local scan -> soff/eoff/dinv -> fill col (bucket-local).
__global__ void bucket_csr_kernel(const int* __restrict__ ebuf0, const int* __restrict__ ebuf1,
                                  const int* __restrict__ bcur, int n, int cap,
                                  int* __restrict__ soff0, int* __restrict__ soff1,
                                  int* __restrict__ eoff0, int* __restrict__ eoff1,
                                  float* __restrict__ dinv0, float* __restrict__ dinv1,
                                  u16* __restrict__ col0, u16* __restrict__ col1) {
    int g = blockIdx.y;
    int b = blockIdx.x;
    const int* ebuf = g ? ebuf1 : ebuf0;
    int* soff = g ? soff1 : soff0;
    int* eoff = g ? eoff1 : eoff0;
    float* dinv = g ? dinv1 : dinv0;
    u16* col = g ? col1 : col0;
    __shared__ int h[BW], nb[BW], nrank[BW];
    int tid = threadIdx.x;
    if (tid < BW) h[tid] = 0;
    __syncthreads();
    int s = b * cap;
    int cnt = min(bcur[g * 1024 + b], cap);
    int e = s + cnt;
    for (int i = s + tid; i < e; i += TPB)
        atomicAdd(&h[ebuf[i] & (BW - 1)], 1);
    __syncthreads();
    if (tid < BW) {
        int v = h[tid];
        int x = v;
        for (int d = 1; d < BW; d <<= 1) {
            int u = __shfl_up(x, d, 64);
            if (tid >= d) x += u;
        }
        int base = s + x - v;  // exclusive prefix within bucket region
        nb[tid] = base;
        nrank[tid] = 0;
        int node = b * BW + tid;
        if (node < n) {
            soff[node] = base;
            eoff[node] = base + v;
            dinv[node] = rsqrtf((float)v + 1.0f);
        }
    }
    __syncthreads();
    for (int i = s + tid; i < e; i += TPB) {
        int p = ebuf[i];
        int lo = p & (BW - 1);
        int r = atomicAdd(&nrank[lo], 1);
        col[nb[lo] + r] = (u16)(p >> SH);
    }
}

// ---------------- dense matmul via MFMA: Y = bf16( dinv[n] * (X @ W) ) ----------

template <int CIN, int COUT>
__global__ void matmul_kernel(const float* __restrict__ X0, const float* __restrict__ X1,
                              const float* __restrict__ W,
                              const float* __restrict__ dinv0, const float* __restrict__ dinv1,
                              u16* __restrict__ Y0, u16* __restrict__ Y1, int n) {
    constexpr int CINP = CIN + 8;
    constexpr int NT = COUT / 16;
    constexpr int KT = CIN / 32;
    __shared__ u16 Xs[64 * CINP];
    __shared__ u16 Wt[COUT * CINP];

    int g = blockIdx.y;
    const float* X = g ? X1 : X0;
    const float* dinv = g ? dinv1 : dinv0;
    u16* Y = g ? Y1 : Y0;
    int nb0 = blockIdx.x * 64;

    for (int i = threadIdx.x; i < 64 * (CIN / 4); i += TPB) {
        int nn = i / (CIN / 4), kc = i % (CIN / 4);
        float4 v = make_float4(0.f, 0.f, 0.f, 0.f);
        if (nb0 + nn < n) v = *(const float4*)&X[(size_t)(nb0 + nn) * CIN + 4 * kc];
        ushort4 b;
        b.x = f_to_bf(v.x); b.y = f_to_bf(v.y); b.z = f_to_bf(v.z); b.w = f_to_bf(v.w);
        *(ushort4*)&Xs[nn * CINP + 4 * kc] = b;
    }
    for (int i = threadIdx.x; i < CIN * (COUT / 4); i += TPB) {
        int k = i / (COUT / 4), nc4 = i % (COUT / 4);
        float4 v = *(const float4*)&W[(size_t)k * COUT + 4 * nc4];
        Wt[(4 * nc4 + 0) * CINP + k] = f_to_bf(v.x);
        Wt[(4 * nc4 + 1) * CINP + k] = f_to_bf(v.y);
        Wt[(4 * nc4 + 2) * CINP + k] = f_to_bf(v.z);
        Wt[(4 * nc4 + 3) * CINP + k] = f_to_bf(v.w);
    }
    __syncthreads();

    int lane = threadIdx.x & 63;
    int w = threadIdx.x >> 6;
    int m = lane & 15;
    int quad = lane >> 4;

    f32x4 acc[NT];
#pragma unroll
    for (int t = 0; t < NT; t++) acc[t] = (f32x4){0.f, 0.f, 0.f, 0.f};
#pragma unroll
    for (int kt = 0; kt < KT; kt++) {
        int k0 = kt * 32 + quad * 8;
        bf16x8 a = *(const bf16x8*)&Xs[(w * 16 + m) * CINP + k0];
#pragma unroll
        for (int t = 0; t < NT; t++) {
            bf16x8 b = *(const bf16x8*)&Wt[(t * 16 + m) * CINP + k0];
            acc[t] = __builtin_amdgcn_mfma_f32_16x16x32_bf16(a, b, acc[t], 0, 0, 0);
        }
    }
#pragma unroll
    for (int r = 0; r < 4; r++) {
        int node = nb0 + w * 16 + quad * 4 + r;
        if (node < n) {
            float d = dinv[node];
#pragma unroll
            for (int t = 0; t < NT; t++)
                Y[(size_t)node * COUT + t * 16 + m] = f_to_bf(acc[t][r] * d);
        }
    }
}

// ------- layer-1 fused agg (C=64, EPG=4 gather) + MFMA layer-2 matmul -------
// Block = 16 nodes, 16 lanes/node: (e in [0,4)) x (cb in [0,4)), each lane owns
// chunks cb and cb+4 (16B each). Per 16-edge batch: 4 col loads + 8 gathers =
// 12 VMEM wave-instrs (vs 16 for the paired-edge scheme) at identical request
// count. Gather+relu -> bf16 H rows in LDS; MFMA epilogue Y = bf16(dinv*(H@W2)).

template <int COUT2>
__global__ __launch_bounds__(TPB, 2)
void agg_mm64_kernel(const u16* __restrict__ HW0, const u16* __restrict__ HW1,
                     const int* __restrict__ soff0, const int* __restrict__ soff1,
                     const int* __restrict__ eoff0, const int* __restrict__ eoff1,
                     const u16* __restrict__ col0, const u16* __restrict__ col1,
                     const float* __restrict__ dinv0, const float* __restrict__ dinv1,
                     const float* __restrict__ bias, const float* __restrict__ W2,
                     u16* __restrict__ Y0, u16* __restrict__ Y1, int n, int nblk) {
    constexpr int C = 64;
    constexpr int CP = C + 8;        // padded LDS row stride (u16), 16B-aligned rows
    constexpr int NT2 = COUT2 / 16;  // MFMA col-tiles
    constexpr int KT2 = C / 32;      // MFMA k-tiles
    __shared__ __align__(16) u16 HsB[16 * CP];
    __shared__ __align__(16) u16 WtB[COUT2 * CP];

    int g, bx;
    if (!swz_block(nblk, g, bx)) return;
    const u16* HW = g ? HW1 : HW0;
    const int* soff = g ? soff1 : soff0;
    const int* eoff = g ? eoff1 : eoff0;
    const u16* col = g ? col1 : col0;
    const float* dinv = g ? dinv1 : dinv0;
    u16* Y = g ? Y1 : Y0;

    // stage W2 transposed (bf16) while gather loads are in flight
    for (int idx = threadIdx.x; idx < C * COUT2; idx += TPB) {
        int k = idx / COUT2, nc = idx % COUT2;
        WtB[nc * CP + k] = f_to_bf(W2[idx]);
    }

    int nl = threadIdx.x >> 4;
    int part = threadIdx.x & 15;
    int e = part & 3;   // edge slot within batch
    int cb = part >> 2; // chunk pair: chunks cb and cb+4
    int node = bx * 16 + nl;

    float a0[8], a1[8], o0[8], o1[8];
#pragma unroll
    for (int i = 0; i < 8; i++) { a0[i] = 0.f; a1[i] = 0.f; o0[i] = 0.f; o1[i] = 0.f; }

    if (node < n) {
        int s = soff[node], en = eoff[node];
        int p = s;
        for (; p + 16 <= en; p += 16) {
            int j[4];
            uint4 d0[4], d1[4];
#pragma unroll
            for (int r = 0; r < 4; r++) j[r] = col[p + 4 * r + e];
#pragma unroll
            for (int r = 0; r < 4; r++) {
                const u16* row = &HW[(size_t)j[r] * C];
                d0[r] = *(const uint4*)&row[cb * 8];
                d1[r] = *(const uint4*)&row[cb * 8 + 32];
            }
#pragma unroll
            for (int r = 0; r < 4; r++) { bacc8(a0, d0[r]); bacc8(a1, d1[r]); }
        }
        for (int q = p + e; q < en; q += 4) {
            const u16* row = &HW[(size_t)col[q] * C];
            bacc8(a0, *(const uint4*)&row[cb * 8]);
            bacc8(a1, *(const uint4*)&row[cb * 8 + 32]);
        }
        red8(a0, 1, 16); red8(a1, 1, 16);
        red8(a0, 2, 16); red8(a1, 2, 16);
        if (e == 0) {  // writer lane per chunk pair
            float di = dinv[node];
            float sv0[8], sv1[8];
            bdec8(*(const uint4*)&HW[(size_t)node * C + cb * 8], sv0);
            bdec8(*(const uint4*)&HW[(size_t)node * C + cb * 8 + 32], sv1);
#pragma unroll
            for (int i = 0; i < 8; i++) {
                o0[i] = fmaxf(di * (a0[i] + sv0[i]) + bias[cb * 8 + i], 0.f);
                o1[i] = fmaxf(di * (a1[i] + sv1[i]) + bias[cb * 8 + 32 + i], 0.f);
            }
        }
    }
    if (e == 0) {  // zeros for tail nodes
        *(uint4*)&HsB[nl * CP + cb * 8] = pack8(o0);
        *(uint4*)&HsB[nl * CP + cb * 8 + 32] = pack8(o1);
    }
    __syncthreads();

    // MFMA epilogue: wave w computes 16 nodes x out-cols [w*16, w*16+16)
    int lane = threadIdx.x & 63;
    int w = threadIdx.x >> 6;
    if (w < NT2) {
        int m = lane & 15;
        int quad = lane >> 4;
        f32x4 ac = (f32x4){0.f, 0.f, 0.f, 0.f};
#pragma unroll
        for (int kt = 0; kt < KT2; kt++) {
            int k0 = kt * 32 + quad * 8;
            bf16x8 a = *(const bf16x8*)&HsB[m * CP + k0];
            bf16x8 b = *(const bf16x8*)&WtB[(w * 16 + m) * CP + k0];
            ac = __builtin_amdgcn_mfma_f32_16x16x32_bf16(a, b, ac, 0, 0, 0);
        }
        int base16 = bx * 16;
#pragma unroll
        for (int r = 0; r < 4; r++) {
            int onode = base16 + quad * 4 + r;
            if (onode < n)
                Y[(size_t)onode * COUT2 + w * 16 + m] = f_to_bf(ac[r] * dinv[onode]);
        }
    }
}

// ------- fused GCN agg (paired-edge 16B gather) + MFMA next-layer matmul -------
// Used for layer 2 (C=32). Block = 16 nodes, lanes (e:2)x(c8:4), SPLIT slices.

template <int C, int SPLIT, int COUT2>
__global__ __launch_bounds__(TPB, 2)
void agg_mm_kernel(const u16* __restrict__ HW0, const u16* __restrict__ HW1,
                   const int* __restrict__ soff0, const int* __restrict__ soff1,
                   const int* __restrict__ eoff0, const int* __restrict__ eoff1,
                   const u16* __restrict__ col0, const u16* __restrict__ col1,
                   const float* __restrict__ dinv0, const float* __restrict__ dinv1,
                   const float* __restrict__ bias, const float* __restrict__ W2,
                   u16* __restrict__ Y0, u16* __restrict__ Y1, int n, int nblk) {
    constexpr int CHUNKS = C / 8;      // 16B chunks per row
    constexpr int GRP = 2 * CHUNKS;    // lanes per slice-group
    constexpr int TPN = GRP * SPLIT;   // 16
    constexpr int CP = C + 8;          // padded LDS row stride (u16)
    constexpr int NT2 = COUT2 / 16;    // MFMA col-tiles
    constexpr int KT2 = C / 32;        // MFMA k-tiles
    __shared__ __align__(16) u16 HsB[16 * CP];
    __shared__ __align__(16) u16 WtB[COUT2 * CP];

    int g, bx;
    if (!swz_block(nblk, g, bx)) return;
    const u16* HW = g ? HW1 : HW0;
    const int* soff = g ? soff1 : soff0;
    const int* eoff = g ? eoff1 : eoff0;
    const u16* col = g ? col1 : col0;
    const float* dinv = g ? dinv1 : dinv0;
    u16* Y = g ? Y1 : Y0;

    // stage W2 transposed (bf16) while gather loads are in flight
    for (int idx = threadIdx.x; idx < C * COUT2; idx += TPB) {
        int k = idx / COUT2, nc = idx % COUT2;
        WtB[nc * CP + k] = f_to_bf(W2[idx]);
    }

    int nl = threadIdx.x >> 4;
    int part = threadIdx.x & 15;
    int sp = part / GRP;
    int gl = part % GRP;
    int e = gl / CHUNKS;
    int c8 = gl % CHUNKS;
    int node = bx * 16 + nl;

    float acc[8], o8[8];
#pragma unroll
    for (int i = 0; i < 8; i++) { acc[i] = 0.f; o8[i] = 0.f; }

    if (node < n) {
        int s = soff[node], en = eoff[node];
        int len = en - s;
        int chunk = (len + SPLIT - 1) / SPLIT;
        int ps = s + sp * chunk;
        int pe = min(ps + chunk, en);
        gather_sum16<C>(HW, col, e, c8, ps, pe, acc);
        red8(acc, CHUNKS, TPN);  // sum the 2 edge-lanes
#pragma unroll
        for (int m = GRP; m < TPN; m <<= 1) red8(acc, m, TPN);  // sum slices
        if (part < CHUNKS) {  // writer lane: holds chunk c8 = part
            float di = dinv[node];
            float sv[8];
            bdec8(*(const uint4*)&HW[(size_t)node * C + part * 8], sv);
            float4 b0 = *(const float4*)&bias[part * 8];
            float4 b1 = *(const float4*)&bias[part * 8 + 4];
            o8[0] = fmaxf(di * (acc[0] + sv[0]) + b0.x, 0.f);
            o8[1] = fmaxf(di * (acc[1] + sv[1]) + b0.y, 0.f);
            o8[2] = fmaxf(di * (acc[2] + sv[2]) + b0.z, 0.f);
            o8[3] = fmaxf(di * (acc[3] + sv[3]) + b0.w, 0.f);
            o8[4] = fmaxf(di * (acc[4] + sv[4]) + b1.x, 0.f);
            o8[5] = fmaxf(di * (acc[5] + sv[5]) + b1.y, 0.f);
            o8[6] = fmaxf(di * (acc[6] + sv[6]) + b1.z, 0.f);
            o8[7] = fmaxf(di * (acc[7] + sv[7]) + b1.w, 0.f);
        }
    }
    if (part < CHUNKS) {  // zeros for tail nodes
        *(uint4*)&HsB[nl * CP + part * 8] = pack8(o8);
    }
    __syncthreads();

    // MFMA epilogue: wave w computes 16 nodes x out-cols [w*16, w*16+16)
    int lane = threadIdx.x & 63;
    int w = threadIdx.x >> 6;
    if (w < NT2) {
        int m = lane & 15;
        int quad = lane >> 4;
        f32x4 ac = (f32x4){0.f, 0.f, 0.f, 0.f};
#pragma unroll
        for (int kt = 0; kt < KT2; kt++) {
            int k0 = kt * 32 + quad * 8;
            bf16x8 a = *(const bf16x8*)&HsB[m * CP + k0];
            bf16x8 b = *(const bf16x8*)&WtB[(w * 16 + m) * CP + k0];
            ac = __builtin_amdgcn_mfma_f32_16x16x32_bf16(a, b, ac, 0, 0, 0);
        }
        int base16 = bx * 16;
#pragma unroll
        for (int r = 0; r < 4; r++) {
            int onode = base16 + quad * 4 + r;
            if (onode < n)
                Y[(size_t)onode * COUT2 + w * 16 + m] = f_to_bf(ac[r] * dinv[onode]);
        }
    }
}

// Layer-3 aggregation (C=16, paired-edge 16B gather, SPLIT=4) + bf16 H3 out +
// per-block colsum partials (NO atomics).
__global__ __launch_bounds__(TPB, 2)
void agg16_kernel(const u16* __restrict__ HW0, const u16* __restrict__ HW1,
                  const int* __restrict__ soff0, const int* __restrict__ soff1,
                  const int* __restrict__ eoff0, const int* __restrict__ eoff1,
                  const u16* __restrict__ col0, const u16* __restrict__ col1,
                  const float* __restrict__ dinv0, const float* __restrict__ dinv1,
                  const float* __restrict__ bias,
                  u16* __restrict__ out0, u16* __restrict__ out1,
                  float* __restrict__ pcol, int n, int nblk) {
    int g, bx;
    if (!swz_block(nblk, g, bx)) return;
    const u16* HW = g ? HW1 : HW0;
    const int* soff = g ? soff1 : soff0;
    const int* eoff = g ? eoff1 : eoff0;
    const u16* col = g ? col1 : col0;
    const float* dinv = g ? dinv1 : dinv0;
    u16* outp = g ? out1 : out0;

    int nl = threadIdx.x >> 4;
    int part = threadIdx.x & 15;
    int sp = part >> 2;       // 4 slices (GRP=4)
    int gl = part & 3;
    int e = gl >> 1;          // CHUNKS=2
    int c8 = gl & 1;
    int node = bx * 16 + nl;

    float acc[8], o8v[8];
#pragma unroll
    for (int i = 0; i < 8; i++) { acc[i] = 0.f; o8v[i] = 0.f; }

    if (node < n) {
        int s = soff[node], en = eoff[node];
        int len = en - s;
        int chunk = (len + 3) >> 2;
        int ps = s + sp * chunk;
        int pe = min(ps + chunk, en);
        gather_sum16<16>(HW, col, e, c8, ps, pe, acc);
        red8(acc, 2, 16);
        red8(acc, 4, 16);
        red8(acc, 8, 16);
        if (part < 2) {
            float di = dinv[node];
            float sv[8];
            bdec8(*(const uint4*)&HW[(size_t)node * 16 + part * 8], sv);
            float4 b0 = *(const float4*)&bias[part * 8];
            float4 b1 = *(const float4*)&bias[part * 8 + 4];
            o8v[0] = di * (acc[0] + sv[0]) + b0.x;
            o8v[1] = di * (acc[1] + sv[1]) + b0.y;
            o8v[2] = di * (acc[2] + sv[2]) + b0.z;
            o8v[3] = di * (acc[3] + sv[3]) + b0.w;
            o8v[4] = di * (acc[4] + sv[4]) + b1.x;
            o8v[5] = di * (acc[5] + sv[5]) + b1.y;
            o8v[6] = di * (acc[6] + sv[6]) + b1.z;
            o8v[7] = di * (acc[7] + sv[7]) + b1.w;
            *(uint4*)&outp[(size_t)node * 16 + part * 8] = pack8(o8v);
        }
    }
    // per-block colsum partial: lanes part<2 hold chunk (part*8..part*8+7)
    __shared__ float4 sa[TPB], sb[TPB];
    bool hold = (node < n) && (part < 2);
    sa[threadIdx.x] = hold ? make_float4(o8v[0], o8v[1], o8v[2], o8v[3])
                           : make_float4(0.f, 0.f, 0.f, 0.f);
    sb[threadIdx.x] = hold ? make_float4(o8v[4], o8v[5], o8v[6], o8v[7])
                           : make_float4(0.f, 0.f, 0.f, 0.f);
    __syncthreads();
    if (threadIdx.x < 64) {
        float4 a = sa[threadIdx.x], b = sb[threadIdx.x];
        facc(a, sa[threadIdx.x + 64]);  facc(b, sb[threadIdx.x + 64]);
        facc(a, sa[threadIdx.x + 128]); facc(b, sb[threadIdx.x + 128]);
        facc(a, sa[threadIdx.x + 192]); facc(b, sb[threadIdx.x + 192]);
        sa[threadIdx.x] = a; sb[threadIdx.x] = b;
    }
    __syncthreads();
    if (threadIdx.x < 16) {
        float4 a = sa[threadIdx.x], b = sb[threadIdx.x];
        facc(a, sa[threadIdx.x + 16]); facc(b, sb[threadIdx.x + 16]);
        facc(a, sa[threadIdx.x + 32]); facc(b, sb[threadIdx.x + 32]);
        facc(a, sa[threadIdx.x + 48]); facc(b, sb[threadIdx.x + 48]);
        sa[threadIdx.x] = a; sb[threadIdx.x] = b;
    }
    __syncthreads();
    if (threadIdx.x < 2) {
        float* dst = &pcol[((size_t)g * nblk + bx) * 16 + threadIdx.x * 8];
        *(float4*)&dst[0] = sa[threadIdx.x];
        *(float4*)&dst[4] = sb[threadIdx.x];
    }
}

// ---------------- cvec: coalesced reduce of pcol partials + tanh(mean @ Wa) ----------

__global__ void cvec_kernel(const float* __restrict__ pcol, int nb16, float n_inv,
                            const float* __restrict__ Wa, float* __restrict__ cvec) {
    int g = blockIdx.x;
    const float4* p4 = (const float4*)(pcol + (size_t)g * nb16 * 16);
    __shared__ float4 sd[TPB];
    __shared__ float cs[16];
    int c4 = threadIdx.x & 3;
    int row = threadIdx.x >> 2;
    float4 acc = make_float4(0.f, 0.f, 0.f, 0.f);
    for (int r = row; r < nb16; r += 64) facc(acc, p4[(size_t)r * 4 + c4]);
    sd[threadIdx.x] = acc;
    __syncthreads();
    if (threadIdx.x < 64) {
        float4 a = sd[threadIdx.x];
        facc(a, sd[threadIdx.x + 64]);
        facc(a, sd[threadIdx.x + 128]);
        facc(a, sd[threadIdx.x + 192]);
        sd[threadIdx.x] = a;
    }
    __syncthreads();
    if (threadIdx.x < 16) {
        float4 a = sd[threadIdx.x];
        facc(a, sd[threadIdx.x + 16]);
        facc(a, sd[threadIdx.x + 32]);
        facc(a, sd[threadIdx.x + 48]);
        sd[threadIdx.x] = a;
    }
    __syncthreads();
    if (threadIdx.x < 4) {
        float4 a = sd[threadIdx.x];
        facc(a, sd[threadIdx.x + 4]);
        facc(a, sd[threadIdx.x + 8]);
        facc(a, sd[threadIdx.x + 12]);
        cs[threadIdx.x * 4 + 0] = a.x * n_inv;
        cs[threadIdx.x * 4 + 1] = a.y * n_inv;
        cs[threadIdx.x * 4 + 2] = a.z * n_inv;
        cs[threadIdx.x * 4 + 3] = a.w * n_inv;
    }
    __syncthreads();
    if (threadIdx.x < 16) {
        float acc2 = 0.f;
#pragma unroll
        for (int i = 0; i < 16; i++) acc2 += cs[i] * Wa[i * 16 + threadIdx.x];
        cvec[g * 16 + threadIdx.x] = tanhf(acc2);
    }
}

// ---------------- attention pooling (bf16 H3, per-block partials) ----------------

__global__ void pool_kernel(const u16* __restrict__ H0, const u16* __restrict__ H1, int n,
                            const float* __restrict__ cvec, float* __restrict__ ppool) {
    int g = blockIdx.y;
    const u16* H = g ? H1 : H0;
    int c = threadIdx.x & 15;
    float cv = cvec[g * 16 + c];
    int w = (blockIdx.x * blockDim.x + threadIdx.x) / 16;
    int stride = (gridDim.x * blockDim.x) / 16;
    float acc = 0.f;
    for (int node = w; node < n; node += stride) {
        float x = __uint_as_float((unsigned)H[(size_t)node * 16 + c] << 16);
        float p = x * cv;
        p += __shfl_xor(p, 1, 16);
        p += __shfl_xor(p, 2, 16);
        p += __shfl_xor(p, 4, 16);
        p += __shfl_xor(p, 8, 16);
        float s = 1.f / (1.f + __expf(-p));
        acc += s * x;
    }
    __shared__ float sdata[TPB];
    sdata[threadIdx.x] = acc;
    __syncthreads();
    if (threadIdx.x < 16) {
        float s = 0.f;
        for (int t = threadIdx.x; t < TPB; t += 16) s += sdata[t];
        ppool[((size_t)g * gridDim.x + blockIdx.x) * 16 + threadIdx.x] = s;
    }
}

// ---------------- final: parallel reduce of pool partials + tensor-network scoring ----

__global__ void final_kernel(const float* __restrict__ ppool, int nbp,
                             const float* __restrict__ Wt, const float* __restrict__ Wb,
                             const float* __restrict__ bt, const float* __restrict__ Wfc,
                             const float* __restrict__ bfc, const float* __restrict__ Wsc,
                             const float* __restrict__ bsc, float* __restrict__ out) {
    __shared__ float4 sd4[TPB];
    __shared__ float rep[32], part[TPB], scores[16], tvec[16];
    int t = threadIdx.x;
    {
        const float4* p4 = (const float4*)ppool;
        int g = t >> 7;
        int r0 = (t >> 2) & 31;
        int c4 = t & 3;
        float4 acc = make_float4(0.f, 0.f, 0.f, 0.f);
        for (int r = r0; r < nbp; r += 32)
            facc(acc, p4[((size_t)g * nbp + r) * 4 + c4]);
        sd4[t] = acc;
        __syncthreads();
        for (int st = 16; st >= 1; st >>= 1) {
            if (r0 < st) facc(sd4[t], sd4[t + st * 4]);
            __syncthreads();
        }
        if (r0 == 0) {
            float4 a = sd4[t];
            rep[g * 16 + c4 * 4 + 0] = a.x;
            rep[g * 16 + c4 * 4 + 1] = a.y;
            rep[g * 16 + c4 * 4 + 2] = a.z;
            rep[g * 16 + c4 * 4 + 3] = a.w;
        }
        __syncthreads();
    }
    {
        int p = t >> 4, tt = t & 15;
        float b = 0.f;
#pragma unroll
        for (int q = 0; q < 16; q++)
            b += rep[q] * Wt[(q * 16 + p) * 16 + tt];
        part[t] = b * rep[16 + p];
    }
    __syncthreads();
    if (t < 16) {
        float bil = 0.f;
#pragma unroll
        for (int p = 0; p < 16; p++) bil += part[p * 16 + t];
        float blk = 0.f;
#pragma unroll
        for (int m = 0; m < 16; m++)
            blk += Wb[t * 32 + m] * rep[m] + Wb[t * 32 + 16 + m] * rep[16 + m];
        scores[t] = fmaxf(bil + blk + bt[t], 0.f);
    }
    __syncthreads();
    if (t < 16) {
        float acc = bfc[t];
#pragma unroll
        for (int k = 0; k < 16; k++) acc += scores[k] * Wfc[k * 16 + t];
        tvec[t] = tanhf(acc);
    }
    __syncthreads();
    if (t == 0) {
        float acc = bsc[0];
#pragma unroll
        for (int j = 0; j < 16; j++) acc += tvec[j] * Wsc[j];
        out[0] = 1.f / (1.f + __expf(-acc));
    }
}

// ---------------- launcher ----------------

extern "C" void kernel_launch(void* const* d_in, const int* in_sizes, int n_in,
                              void* d_out, int out_size, void* d_ws, size_t ws_size,
                              hipStream_t stream) {
    const float* X1 = (const float*)d_in[0];
    const float* X2 = (const float*)d_in[1];
    const int* edges1 = (const int*)d_in[2];
    const int* edges2 = (const int*)d_in[3];
    const float* W1 = (const float*)d_in[4];
    const float* b1 = (const float*)d_in[5];
    const float* W2 = (const float*)d_in[6];
    const float* b2 = (const float*)d_in[7];
    const float* W3 = (const float*)d_in[8];
    const float* b3 = (const float*)d_in[9];
    const float* Wa = (const float*)d_in[10];
    const float* Wt = (const float*)d_in[11];
    const float* Wb = (const float*)d_in[12];
    const float* bt = (const float*)d_in[13];
    const float* Wfc = (const float*)d_in[14];
    const float* bfc = (const float*)d_in[15];
    const float* Wsc = (const float*)d_in[16];
    const float* bsc = (const float*)d_in[17];
    float* out = (float*)d_out;

    const int N = in_sizes[0] / 96;
    const int E = in_sizes[2] / 2;
    const int NBUK = (N + BW - 1) / BW;  // buckets (must be <= 1024)
    int cap = ((2 * (E / NBUK)) + 255) & ~255;  // bucket capacity: 2x average, safe
    if (cap < 256) cap = 256;

    char* ws = (char*)d_ws;
    size_t o = 0;
    auto alloc = [&](size_t bytes) {
        void* p = ws + o;
        o += (bytes + 255) & ~(size_t)255;
        return p;
    };
    int* bcur = (int*)alloc((size_t)2 * 1024 * 4);
    int* soff0 = (int*)alloc((size_t)N * 4);
    int* soff1 = (int*)alloc((size_t)N * 4);
    int* eoff0 = (int*)alloc((size_t)N * 4);
    int* eoff1 = (int*)alloc((size_t)N * 4);
    u16* col0 = (u16*)alloc((size_t)NBUK * cap * 2);
    u16* col1 = (u16*)alloc((size_t)NBUK * cap * 2);
    int* ebuf0 = (int*)alloc((size_t)NBUK * cap * 4);
    int* ebuf1 = (int*)alloc((size_t)NBUK * cap * 4);
    float* dinv0 = (float*)alloc((size_t)N * 4);
    float* dinv1 = (float*)alloc((size_t)N * 4);
    u16* hwbA0 = (u16*)alloc((size_t)N * 64 * 2);  // layer-1 payload
    u16* hwbA1 = (u16*)alloc((size_t)N * 64 * 2);
    u16* hwbB0 = (u16*)alloc((size_t)N * 32 * 2);  // layer-2 payload
    u16* hwbB1 = (u16*)alloc((size_t)N * 32 * 2);
    u16* hwbC0 = (u16*)alloc((size_t)N * 16 * 2);  // layer-3 payload
    u16* hwbC1 = (u16*)alloc((size_t)N * 16 * 2);
    u16* H30 = (u16*)alloc((size_t)N * 16 * 2);  // H3 bf16 (pool input)
    u16* H31 = (u16*)alloc((size_t)N * 16 * 2);

    const int gB2 = (E + 4095) / 4096;
    const int g16 = ((size_t)N * 16 + TPB - 1) / TPB;  // aggs: 16 threads/node
    const int gSwz = 8 * ((g16 + 3) / 4);              // 4-XCD-per-graph swizzled grid
    const int gMM = (N + 63) / 64;
    const int gPool = 256;

    float* pcol = (float*)alloc((size_t)2 * g16 * 16 * 4);
    float* cvecArr = (float*)alloc(32 * 4);
    float* ppool = (float*)alloc((size_t)2 * gPool * 16 * 4);

    hipMemsetAsync(bcur, 0, (size_t)2 * 1024 * 4, stream);

    // capacity-bucket CSR build: scatter -> per-bucket finalize (no count/scan passes)
    bucket_scatter_kernel<<<dim3(gB2, 2), TPB, 0, stream>>>(edges1, edges2, E, bcur,
                                                            ebuf0, ebuf1, NBUK, cap);
    bucket_csr_kernel<<<dim3(NBUK, 2), TPB, 0, stream>>>(ebuf0, ebuf1, bcur, N, cap,
                                                         soff0, soff1, eoff0, eoff1,
                                                         dinv0, dinv1, col0, col1);

    // layer 1 matmul (MFMA 96->64)
    matmul_kernel<96, 64><<<dim3(gMM, 2), TPB, 0, stream>>>(X1, X2, W1, dinv0, dinv1,
                                                            hwbA0, hwbA1, N);
    // layer-1 agg (EPG=4 gather) + fused layer-2 MFMA matmul (64 -> H1 -> @W2 -> 32)
    agg_mm64_kernel<32><<<gSwz, TPB, 0, stream>>>(
        hwbA0, hwbA1, soff0, soff1, eoff0, eoff1, col0, col1, dinv0, dinv1, b1, W2,
        hwbB0, hwbB1, N, g16);
    // layer-2 agg + fused layer-3 MFMA matmul (32 -> H2 -> @W3 -> 16 bf16)
    agg_mm_kernel<32, 2, 16><<<gSwz, TPB, 0, stream>>>(
        hwbB0, hwbB1, soff0, soff1, eoff0, eoff1, col0, col1, dinv0, dinv1, b2, W3,
        hwbC0, hwbC1, N, g16);
    // layer-3 agg (writes H3 bf16 + colsum partials)
    agg16_kernel<<<gSwz, TPB, 0, stream>>>(
        hwbC0, hwbC1, soff0, soff1, eoff0, eoff1, col0, col1, dinv0, dinv1, b3,
        H30, H31, pcol, N, g16);

    // attention pooling + scoring
    cvec_kernel<<<2, TPB, 0, stream>>>(pcol, g16, 1.0f / (float)N, Wa, cvecArr);
    pool_kernel<<<dim3(gPool, 2), TPB, 0, stream>>>(H30, H31, N, cvecArr, ppool);
    final_kernel<<<1, 256, 0, stream>>>(ppool, gPool, Wt, Wb, bt, Wfc, bfc, Wsc, bsc, out);
}

// Round 8
// 253.854 us; speedup vs baseline: 1.0731x; 1.0321x over previous
//
#include <hip/hip_runtime.h>
#include <hip/hip_bf16.h>

#define TPB 256
#define SH 6
#define BW 64  // nodes per bucket = 1<<SH; NBUK must be <= 1024 (N <= 65536)

typedef unsigned short u16;
typedef __attribute__((ext_vector_type(8))) __bf16 bf16x8;  // MFMA A/B frag (4 VGPRs)
typedef __attribute__((ext_vector_type(4))) float f32x4;    // MFMA C/D frag

// bf16 helpers: payload stored as bf16 (halves gather BW), accumulate in fp32.
__device__ __forceinline__ u16 f_to_bf(float f) {
    unsigned u = __float_as_uint(f);
    return (u16)((u + 0x7fff + ((u >> 16) & 1)) >> 16);  // RNE
}
__device__ __forceinline__ unsigned pkbf(float a, float b) {
    return (unsigned)f_to_bf(a) | ((unsigned)f_to_bf(b) << 16);
}
__device__ __forceinline__ void facc(float4& a, float4 v) {
    a.x += v.x; a.y += v.y; a.z += v.z; a.w += v.w;
}

// 16B bf16 chunk (8 channels) decode/accumulate
__device__ __forceinline__ void bacc8(float* __restrict__ a, uint4 d) {
    a[0] += __uint_as_float(d.x << 16);
    a[1] += __uint_as_float(d.x & 0xffff0000u);
    a[2] += __uint_as_float(d.y << 16);
    a[3] += __uint_as_float(d.y & 0xffff0000u);
    a[4] += __uint_as_float(d.z << 16);
    a[5] += __uint_as_float(d.z & 0xffff0000u);
    a[6] += __uint_as_float(d.w << 16);
    a[7] += __uint_as_float(d.w & 0xffff0000u);
}
__device__ __forceinline__ void bdec8(uint4 d, float* __restrict__ f) {
    f[0] = __uint_as_float(d.x << 16);
    f[1] = __uint_as_float(d.x & 0xffff0000u);
    f[2] = __uint_as_float(d.y << 16);
    f[3] = __uint_as_float(d.y & 0xffff0000u);
    f[4] = __uint_as_float(d.z << 16);
    f[5] = __uint_as_float(d.z & 0xffff0000u);
    f[6] = __uint_as_float(d.w << 16);
    f[7] = __uint_as_float(d.w & 0xffff0000u);
}
__device__ __forceinline__ void red8(float* __restrict__ a, int mask, int width) {
#pragma unroll
    for (int i = 0; i < 8; i++) a[i] += __shfl_xor(a[i], mask, width);
}
__device__ __forceinline__ uint4 pack8(const float* __restrict__ o) {
    uint4 h;
    h.x = pkbf(o[0], o[1]); h.y = pkbf(o[2], o[3]);
    h.z = pkbf(o[4], o[5]); h.w = pkbf(o[6], o[7]);
    return h;
}

// XCD-aware block swizzle (4 XCDs per graph): blk&7 = XCD on MI355X.
__device__ __forceinline__ bool swz_block(int nblk, int& g, int& bx) {
    int blk = blockIdx.x;
    int j = blk & 7;
    g = j >> 2;
    bx = (blk >> 3) * 4 + (j & 3);
    return bx < nblk;
}

// ---- 16B/lane paired-edge gather (EPG=2; round-5 proven config) ----
// Group of 2*CHUNKS lanes tiles (2 edges) x (C/8 16B-chunks). u16 col indices.
// Per 8-edge batch: 4 col loads + 4 uint4 gathers = 8 VMEM wave-instrs.
template <int C>
__device__ __forceinline__ void gather_sum16(const u16* __restrict__ HW,
                                             const u16* __restrict__ col,
                                             int e, int c8, int ps, int pe,
                                             float* __restrict__ acc) {
    int p = ps;
    for (; p + 8 <= pe; p += 8) {
        int j[4];
        uint4 d[4];
#pragma unroll
        for (int r = 0; r < 4; r++) j[r] = col[p + 2 * r + e];
#pragma unroll
        for (int r = 0; r < 4; r++) d[r] = *(const uint4*)&HW[(size_t)j[r] * C + c8 * 8];
#pragma unroll
        for (int r = 0; r < 4; r++) bacc8(acc, d[r]);
    }
    for (; p + 2 <= pe; p += 2) {
        int j = col[p + e];
        bacc8(acc, *(const uint4*)&HW[(size_t)j * C + c8 * 8]);
    }
    if (p < pe && e == 0) {
        int j = col[p];
        bacc8(acc, *(const uint4*)&HW[(size_t)j * C + c8 * 8]);
    }
}

// ---------------- capacity-bucket CSR build (no count/scan passes) ----------------

__global__ void bucket_scatter_kernel(const int* __restrict__ e0, const int* __restrict__ e1,
                                      int E, int* __restrict__ bcur,
                                      int* __restrict__ ebuf0, int* __restrict__ ebuf1,
                                      int nbuk, int cap) {
    int g = blockIdx.y;
    const int* src = g ? e1 : e0;
    const int* dst = src + E;
    int* ebuf = g ? ebuf1 : ebuf0;
    int* bu = bcur + g * 1024;
    __shared__ int hist[1024];
    for (int t = threadIdx.x; t < 1024; t += TPB) hist[t] = 0;
    __syncthreads();
    int base = blockIdx.x * 4096;
    int pk[16], bk[16], rk[16];
#pragma unroll
    for (int k = 0; k < 16; k++) {
        int e = base + k * TPB + (int)threadIdx.x;
        bk[k] = -1;
        if (e < E) {
            int s = src[e], d = dst[e];
            int b = d >> SH;
            bk[k] = b;
            pk[k] = (s << SH) | (d & (BW - 1));
            rk[k] = atomicAdd(&hist[b], 1);
        }
    }
    __syncthreads();
    for (int t = threadIdx.x; t < nbuk; t += TPB) {
        int h = hist[t];
        hist[t] = h ? atomicAdd(&bu[t], h) : 0;
    }
    __syncthreads();
#pragma unroll
    for (int k = 0; k < 16; k++)
        if (bk[k] >= 0) {
            int pos = hist[bk[k]] + rk[k];
            if (pos < cap) ebuf[(size_t)bk[k] * cap + pos] = pk[k];
        }
}

// Per-bucket: histogram -> local scan -> soff/eoff/dinv -> fill col (bucket-local).
__global__ void bucket_csr_kernel(const int* __restrict__ ebuf0, const int* __restrict__ ebuf1,
                                  const int* __restrict__ bcur, int n, int cap,
                                  int* __restrict__ soff0, int* __restrict__ soff1,
                                  int* __restrict__ eoff0, int* __restrict__ eoff1,
                                  float* __restrict__ dinv0, float* __restrict__ dinv1,
                                  u16* __restrict__ col0, u16* __restrict__ col1) {
    int g = blockIdx.y;
    int b = blockIdx.x;
    const int* ebuf = g ? ebuf1 : ebuf0;
    int* soff = g ? soff1 : soff0;
    int* eoff = g ? eoff1 : eoff0;
    float* dinv = g ? dinv1 : dinv0;
    u16* col = g ? col1 : col0;
    __shared__ int h[BW], nb[BW], nrank[BW];
    int tid = threadIdx.x;
    if (tid < BW) h[tid] = 0;
    __syncthreads();
    int s = b * cap;
    int cnt = min(bcur[g * 1024 + b], cap);
    int e = s + cnt;
    for (int i = s + tid; i < e; i += TPB)
        atomicAdd(&h[ebuf[i] & (BW - 1)], 1);
    __syncthreads();
    if (tid < BW) {
        int v = h[tid];
        int x = v;
        for (int d = 1; d < BW; d <<= 1) {
            int u = __shfl_up(x, d, 64);
            if (tid >= d) x += u;
        }
        int base = s + x - v;  // exclusive prefix within bucket region
        nb[tid] = base;
        nrank[tid] = 0;
        int node = b * BW + tid;
        if (node < n) {
            soff[node] = base;
            eoff[node] = base + v;
            dinv[node] = rsqrtf((float)v + 1.0f);
        }
    }
    __syncthreads();
    for (int i = s + tid; i < e; i += TPB) {
        int p = ebuf[i];
        int lo = p & (BW - 1);
        int r = atomicAdd(&nrank[lo], 1);
        col[nb[lo] + r] = (u16)(p >> SH);
    }
}

// ---------------- dense matmul via MFMA: Y = bf16( dinv[n] * (X @ W) ) ----------

template <int CIN, int COUT>
__global__ void matmul_kernel(const float* __restrict__ X0, const float* __restrict__ X1,
                              const float* __restrict__ W,
                              const float* __restrict__ dinv0, const float* __restrict__ dinv1,
                              u16* __restrict__ Y0, u16* __restrict__ Y1, int n) {
    constexpr int CINP = CIN + 8;
    constexpr int NT = COUT / 16;
    constexpr int KT = CIN / 32;
    __shared__ u16 Xs[64 * CINP];
    __shared__ u16 Wt[COUT * CINP];

    int g = blockIdx.y;
    const float* X = g ? X1 : X0;
    const float* dinv = g ? dinv1 : dinv0;
    u16* Y = g ? Y1 : Y0;
    int nb0 = blockIdx.x * 64;

    for (int i = threadIdx.x; i < 64 * (CIN / 4); i += TPB) {
        int nn = i / (CIN / 4), kc = i % (CIN / 4);
        float4 v = make_float4(0.f, 0.f, 0.f, 0.f);
        if (nb0 + nn < n) v = *(const float4*)&X[(size_t)(nb0 + nn) * CIN + 4 * kc];
        ushort4 b;
        b.x = f_to_bf(v.x); b.y = f_to_bf(v.y); b.z = f_to_bf(v.z); b.w = f_to_bf(v.w);
        *(ushort4*)&Xs[nn * CINP + 4 * kc] = b;
    }
    for (int i = threadIdx.x; i < CIN * (COUT / 4); i += TPB) {
        int k = i / (COUT / 4), nc4 = i % (COUT / 4);
        float4 v = *(const float4*)&W[(size_t)k * COUT + 4 * nc4];
        Wt[(4 * nc4 + 0) * CINP + k] = f_to_bf(v.x);
        Wt[(4 * nc4 + 1) * CINP + k] = f_to_bf(v.y);
        Wt[(4 * nc4 + 2) * CINP + k] = f_to_bf(v.z);
        Wt[(4 * nc4 + 3) * CINP + k] = f_to_bf(v.w);
    }
    __syncthreads();

    int lane = threadIdx.x & 63;
    int w = threadIdx.x >> 6;
    int m = lane & 15;
    int quad = lane >> 4;

    f32x4 acc[NT];
#pragma unroll
    for (int t = 0; t < NT; t++) acc[t] = (f32x4){0.f, 0.f, 0.f, 0.f};
#pragma unroll
    for (int kt = 0; kt < KT; kt++) {
        int k0 = kt * 32 + quad * 8;
        bf16x8 a = *(const bf16x8*)&Xs[(w * 16 + m) * CINP + k0];
#pragma unroll
        for (int t = 0; t < NT; t++) {
            bf16x8 b = *(const bf16x8*)&Wt[(t * 16 + m) * CINP + k0];
            acc[t] = __builtin_amdgcn_mfma_f32_16x16x32_bf16(a, b, acc[t], 0, 0, 0);
        }
    }
#pragma unroll
    for (int r = 0; r < 4; r++) {
        int node = nb0 + w * 16 + quad * 4 + r;
        if (node < n) {
            float d = dinv[node];
#pragma unroll
            for (int t = 0; t < NT; t++)
                Y[(size_t)node * COUT + t * 16 + m] = f_to_bf(acc[t][r] * d);
        }
    }
}

// ------- fused GCN agg (paired-edge 16B gather) + MFMA next-layer matmul -------
// Block = 16 nodes (TPN=16 threads/node). Lane tiling per slice-group:
// (e in {0,1}) x (c8 in [0,C/8)). Gather+relu -> bf16 H rows in LDS; MFMA epilogue
// computes Y = bf16(dinv * (H @ W2)).

template <int C, int SPLIT, int COUT2>
__global__ __launch_bounds__(TPB, 2)
void agg_mm_kernel(const u16* __restrict__ HW0, const u16* __restrict__ HW1,
                   const int* __restrict__ soff0, const int* __restrict__ soff1,
                   const int* __restrict__ eoff0, const int* __restrict__ eoff1,
                   const u16* __restrict__ col0, const u16* __restrict__ col1,
                   const float* __restrict__ dinv0, const float* __restrict__ dinv1,
                   const float* __restrict__ bias, const float* __restrict__ W2,
                   u16* __restrict__ Y0, u16* __restrict__ Y1, int n, int nblk) {
    constexpr int CHUNKS = C / 8;      // 16B chunks per row
    constexpr int GRP = 2 * CHUNKS;    // lanes per slice-group
    constexpr int TPN = GRP * SPLIT;   // 16
    constexpr int CP = C + 8;          // padded LDS row stride (u16)
    constexpr int NT2 = COUT2 / 16;    // MFMA col-tiles
    constexpr int KT2 = C / 32;        // MFMA k-tiles
    __shared__ __align__(16) u16 HsB[16 * CP];
    __shared__ __align__(16) u16 WtB[COUT2 * CP];

    int g, bx;
    if (!swz_block(nblk, g, bx)) return;
    const u16* HW = g ? HW1 : HW0;
    const int* soff = g ? soff1 : soff0;
    const int* eoff = g ? eoff1 : eoff0;
    const u16* col = g ? col1 : col0;
    const float* dinv = g ? dinv1 : dinv0;
    u16* Y = g ? Y1 : Y0;

    // stage W2 transposed (bf16) while gather loads are in flight
    for (int idx = threadIdx.x; idx < C * COUT2; idx += TPB) {
        int k = idx / COUT2, nc = idx % COUT2;
        WtB[nc * CP + k] = f_to_bf(W2[idx]);
    }

    int nl = threadIdx.x >> 4;
    int part = threadIdx.x & 15;
    int sp = part / GRP;
    int gl = part % GRP;
    int e = gl / CHUNKS;
    int c8 = gl % CHUNKS;
    int node = bx * 16 + nl;

    float acc[8], o8[8];
#pragma unroll
    for (int i = 0; i < 8; i++) { acc[i] = 0.f; o8[i] = 0.f; }

    if (node < n) {
        int s = soff[node], en = eoff[node];
        int len = en - s;
        int chunk = (len + SPLIT - 1) / SPLIT;
        int ps = s + sp * chunk;
        int pe = min(ps + chunk, en);
        gather_sum16<C>(HW, col, e, c8, ps, pe, acc);
        red8(acc, CHUNKS, TPN);  // sum the 2 edge-lanes
#pragma unroll
        for (int m = GRP; m < TPN; m <<= 1) red8(acc, m, TPN);  // sum slices
        if (part < CHUNKS) {  // writer lane: holds chunk c8 = part
            float di = dinv[node];
            float sv[8];
            bdec8(*(const uint4*)&HW[(size_t)node * C + part * 8], sv);
            float4 b0 = *(const float4*)&bias[part * 8];
            float4 b1 = *(const float4*)&bias[part * 8 + 4];
            o8[0] = fmaxf(di * (acc[0] + sv[0]) + b0.x, 0.f);
            o8[1] = fmaxf(di * (acc[1] + sv[1]) + b0.y, 0.f);
            o8[2] = fmaxf(di * (acc[2] + sv[2]) + b0.z, 0.f);
            o8[3] = fmaxf(di * (acc[3] + sv[3]) + b0.w, 0.f);
            o8[4] = fmaxf(di * (acc[4] + sv[4]) + b1.x, 0.f);
            o8[5] = fmaxf(di * (acc[5] + sv[5]) + b1.y, 0.f);
            o8[6] = fmaxf(di * (acc[6] + sv[6]) + b1.z, 0.f);
            o8[7] = fmaxf(di * (acc[7] + sv[7]) + b1.w, 0.f);
        }
    }
    if (part < CHUNKS) {  // zeros for tail nodes
        *(uint4*)&HsB[nl * CP + part * 8] = pack8(o8);
    }
    __syncthreads();

    // MFMA epilogue: wave w computes 16 nodes x out-cols [w*16, w*16+16)
    int lane = threadIdx.x & 63;
    int w = threadIdx.x >> 6;
    if (w < NT2) {
        int m = lane & 15;
        int quad = lane >> 4;
        f32x4 ac = (f32x4){0.f, 0.f, 0.f, 0.f};
#pragma unroll
        for (int kt = 0; kt < KT2; kt++) {
            int k0 = kt * 32 + quad * 8;
            bf16x8 a = *(const bf16x8*)&HsB[m * CP + k0];
            bf16x8 b = *(const bf16x8*)&WtB[(w * 16 + m) * CP + k0];
            ac = __builtin_amdgcn_mfma_f32_16x16x32_bf16(a, b, ac, 0, 0, 0);
        }
        int base16 = bx * 16;
#pragma unroll
        for (int r = 0; r < 4; r++) {
            int onode = base16 + quad * 4 + r;
            if (onode < n)
                Y[(size_t)onode * COUT2 + w * 16 + m] = f_to_bf(ac[r] * dinv[onode]);
        }
    }
}

// Layer-3 aggregation (C=16, paired-edge 16B gather, SPLIT=4) + bf16 H3 out +
// per-block colsum partials (NO atomics).
__global__ __launch_bounds__(TPB, 2)
void agg16_kernel(const u16* __restrict__ HW0, const u16* __restrict__ HW1,
                  const int* __restrict__ soff0, const int* __restrict__ soff1,
                  const int* __restrict__ eoff0, const int* __restrict__ eoff1,
                  const u16* __restrict__ col0, const u16* __restrict__ col1,
                  const float* __restrict__ dinv0, const float* __restrict__ dinv1,
                  const float* __restrict__ bias,
                  u16* __restrict__ out0, u16* __restrict__ out1,
                  float* __restrict__ pcol, int n, int nblk) {
    int g, bx;
    if (!swz_block(nblk, g, bx)) return;
    const u16* HW = g ? HW1 : HW0;
    const int* soff = g ? soff1 : soff0;
    const int* eoff = g ? eoff1 : eoff0;
    const u16* col = g ? col1 : col0;
    const float* dinv = g ? dinv1 : dinv0;
    u16* outp = g ? out1 : out0;

    int nl = threadIdx.x >> 4;
    int part = threadIdx.x & 15;
    int sp = part >> 2;       // 4 slices (GRP=4)
    int gl = part & 3;
    int e = gl >> 1;          // CHUNKS=2
    int c8 = gl & 1;
    int node = bx * 16 + nl;

    float acc[8], o8v[8];
#pragma unroll
    for (int i = 0; i < 8; i++) { acc[i] = 0.f; o8v[i] = 0.f; }

    if (node < n) {
        int s = soff[node], en = eoff[node];
        int len = en - s;
        int chunk = (len + 3) >> 2;
        int ps = s + sp * chunk;
        int pe = min(ps + chunk, en);
        gather_sum16<16>(HW, col, e, c8, ps, pe, acc);
        red8(acc, 2, 16);
        red8(acc, 4, 16);
        red8(acc, 8, 16);
        if (part < 2) {
            float di = dinv[node];
            float sv[8];
            bdec8(*(const uint4*)&HW[(size_t)node * 16 + part * 8], sv);
            float4 b0 = *(const float4*)&bias[part * 8];
            float4 b1 = *(const float4*)&bias[part * 8 + 4];
            o8v[0] = di * (acc[0] + sv[0]) + b0.x;
            o8v[1] = di * (acc[1] + sv[1]) + b0.y;
            o8v[2] = di * (acc[2] + sv[2]) + b0.z;
            o8v[3] = di * (acc[3] + sv[3]) + b0.w;
            o8v[4] = di * (acc[4] + sv[4]) + b1.x;
            o8v[5] = di * (acc[5] + sv[5]) + b1.y;
            o8v[6] = di * (acc[6] + sv[6]) + b1.z;
            o8v[7] = di * (acc[7] + sv[7]) + b1.w;
            *(uint4*)&outp[(size_t)node * 16 + part * 8] = pack8(o8v);
        }
    }
    // per-block colsum partial: lanes part<2 hold chunk (part*8..part*8+7)
    __shared__ float4 sa[TPB], sb[TPB];
    bool hold = (node < n) && (part < 2);
    sa[threadIdx.x] = hold ? make_float4(o8v[0], o8v[1], o8v[2], o8v[3])
                           : make_float4(0.f, 0.f, 0.f, 0.f);
    sb[threadIdx.x] = hold ? make_float4(o8v[4], o8v[5], o8v[6], o8v[7])
                           : make_float4(0.f, 0.f, 0.f, 0.f);
    __syncthreads();
    if (threadIdx.x < 64) {
        float4 a = sa[threadIdx.x], b = sb[threadIdx.x];
        facc(a, sa[threadIdx.x + 64]);  facc(b, sb[threadIdx.x + 64]);
        facc(a, sa[threadIdx.x + 128]); facc(b, sb[threadIdx.x + 128]);
        facc(a, sa[threadIdx.x + 192]); facc(b, sb[threadIdx.x + 192]);
        sa[threadIdx.x] = a; sb[threadIdx.x] = b;
    }
    __syncthreads();
    if (threadIdx.x < 16) {
        float4 a = sa[threadIdx.x], b = sb[threadIdx.x];
        facc(a, sa[threadIdx.x + 16]); facc(b, sb[threadIdx.x + 16]);
        facc(a, sa[threadIdx.x + 32]); facc(b, sb[threadIdx.x + 32]);
        facc(a, sa[threadIdx.x + 48]); facc(b, sb[threadIdx.x + 48]);
        sa[threadIdx.x] = a; sb[threadIdx.x] = b;
    }
    __syncthreads();
    if (threadIdx.x < 2) {
        float* dst = &pcol[((size_t)g * nblk + bx) * 16 + threadIdx.x * 8];
        *(float4*)&dst[0] = sa[threadIdx.x];
        *(float4*)&dst[4] = sb[threadIdx.x];
    }
}

// ---------------- cvec: coalesced reduce of pcol partials + tanh(mean @ Wa) ----------

__global__ void cvec_kernel(const float* __restrict__ pcol, int nb16, float n_inv,
                            const float* __restrict__ Wa, float* __restrict__ cvec) {
    int g = blockIdx.x;
    const float4* p4 = (const float4*)(pcol + (size_t)g * nb16 * 16);
    __shared__ float4 sd[TPB];
    __shared__ float cs[16];
    int c4 = threadIdx.x & 3;
    int row = threadIdx.x >> 2;
    float4 acc = make_float4(0.f, 0.f, 0.f, 0.f);
    for (int r = row; r < nb16; r += 64) facc(acc, p4[(size_t)r * 4 + c4]);
    sd[threadIdx.x] = acc;
    __syncthreads();
    if (threadIdx.x < 64) {
        float4 a = sd[threadIdx.x];
        facc(a, sd[threadIdx.x + 64]);
        facc(a, sd[threadIdx.x + 128]);
        facc(a, sd[threadIdx.x + 192]);
        sd[threadIdx.x] = a;
    }
    __syncthreads();
    if (threadIdx.x < 16) {
        float4 a = sd[threadIdx.x];
        facc(a, sd[threadIdx.x + 16]);
        facc(a, sd[threadIdx.x + 32]);
        facc(a, sd[threadIdx.x + 48]);
        sd[threadIdx.x] = a;
    }
    __syncthreads();
    if (threadIdx.x < 4) {
        float4 a = sd[threadIdx.x];
        facc(a, sd[threadIdx.x + 4]);
        facc(a, sd[threadIdx.x + 8]);
        facc(a, sd[threadIdx.x + 12]);
        cs[threadIdx.x * 4 + 0] = a.x * n_inv;
        cs[threadIdx.x * 4 + 1] = a.y * n_inv;
        cs[threadIdx.x * 4 + 2] = a.z * n_inv;
        cs[threadIdx.x * 4 + 3] = a.w * n_inv;
    }
    __syncthreads();
    if (threadIdx.x < 16) {
        float acc2 = 0.f;
#pragma unroll
        for (int i = 0; i < 16; i++) acc2 += cs[i] * Wa[i * 16 + threadIdx.x];
        cvec[g * 16 + threadIdx.x] = tanhf(acc2);
    }
}

// ---------------- attention pooling (bf16 H3, per-block partials) ----------------

__global__ void pool_kernel(const u16* __restrict__ H0, const u16* __restrict__ H1, int n,
                            const float* __restrict__ cvec, float* __restrict__ ppool) {
    int g = blockIdx.y;
    const u16* H = g ? H1 : H0;
    int c = threadIdx.x & 15;
    float cv = cvec[g * 16 + c];
    int w = (blockIdx.x * blockDim.x + threadIdx.x) / 16;
    int stride = (gridDim.x * blockDim.x) / 16;
    float acc = 0.f;
    for (int node = w; node < n; node += stride) {
        float x = __uint_as_float((unsigned)H[(size_t)node * 16 + c] << 16);
        float p = x * cv;
        p += __shfl_xor(p, 1, 16);
        p += __shfl_xor(p, 2, 16);
        p += __shfl_xor(p, 4, 16);
        p += __shfl_xor(p, 8, 16);
        float s = 1.f / (1.f + __expf(-p));
        acc += s * x;
    }
    __shared__ float sdata[TPB];
    sdata[threadIdx.x] = acc;
    __syncthreads();
    if (threadIdx.x < 16) {
        float s = 0.f;
        for (int t = threadIdx.x; t < TPB; t += 16) s += sdata[t];
        ppool[((size_t)g * gridDim.x + blockIdx.x) * 16 + threadIdx.x] = s;
    }
}

// ---------------- final: parallel reduce of pool partials + tensor-network scoring ----

__global__ void final_kernel(const float* __restrict__ ppool, int nbp,
                             const float* __restrict__ Wt, const float* __restrict__ Wb,
                             const float* __restrict__ bt, const float* __restrict__ Wfc,
                             const float* __restrict__ bfc, const float* __restrict__ Wsc,
                             const float* __restrict__ bsc, float* __restrict__ out) {
    __shared__ float4 sd4[TPB];
    __shared__ float rep[32], part[TPB], scores[16], tvec[16];
    int t = threadIdx.x;
    {
        const float4* p4 = (const float4*)ppool;
        int g = t >> 7;
        int r0 = (t >> 2) & 31;
        int c4 = t & 3;
        float4 acc = make_float4(0.f, 0.f, 0.f, 0.f);
        for (int r = r0; r < nbp; r += 32)
            facc(acc, p4[((size_t)g * nbp + r) * 4 + c4]);
        sd4[t] = acc;
        __syncthreads();
        for (int st = 16; st >= 1; st >>= 1) {
            if (r0 < st) facc(sd4[t], sd4[t + st * 4]);
            __syncthreads();
        }
        if (r0 == 0) {
            float4 a = sd4[t];
            rep[g * 16 + c4 * 4 + 0] = a.x;
            rep[g * 16 + c4 * 4 + 1] = a.y;
            rep[g * 16 + c4 * 4 + 2] = a.z;
            rep[g * 16 + c4 * 4 + 3] = a.w;
        }
        __syncthreads();
    }
    {
        int p = t >> 4, tt = t & 15;
        float b = 0.f;
#pragma unroll
        for (int q = 0; q < 16; q++)
            b += rep[q] * Wt[(q * 16 + p) * 16 + tt];
        part[t] = b * rep[16 + p];
    }
    __syncthreads();
    if (t < 16) {
        float bil = 0.f;
#pragma unroll
        for (int p = 0; p < 16; p++) bil += part[p * 16 + t];
        float blk = 0.f;
#pragma unroll
        for (int m = 0; m < 16; m++)
            blk += Wb[t * 32 + m] * rep[m] + Wb[t * 32 + 16 + m] * rep[16 + m];
        scores[t] = fmaxf(bil + blk + bt[t], 0.f);
    }
    __syncthreads();
    if (t < 16) {
        float acc = bfc[t];
#pragma unroll
        for (int k = 0; k < 16; k++) acc += scores[k] * Wfc[k * 16 + t];
        tvec[t] = tanhf(acc);
    }
    __syncthreads();
    if (t == 0) {
        float acc = bsc[0];
#pragma unroll
        for (int j = 0; j < 16; j++) acc += tvec[j] * Wsc[j];
        out[0] = 1.f / (1.f + __expf(-acc));
    }
}

// ---------------- launcher ----------------

extern "C" void kernel_launch(void* const* d_in, const int* in_sizes, int n_in,
                              void* d_out, int out_size, void* d_ws, size_t ws_size,
                              hipStream_t stream) {
    const float* X1 = (const float*)d_in[0];
    const float* X2 = (const float*)d_in[1];
    const int* edges1 = (const int*)d_in[2];
    const int* edges2 = (const int*)d_in[3];
    const float* W1 = (const float*)d_in[4];
    const float* b1 = (const float*)d_in[5];
    const float* W2 = (const float*)d_in[6];
    const float* b2 = (const float*)d_in[7];
    const float* W3 = (const float*)d_in[8];
    const float* b3 = (const float*)d_in[9];
    const float* Wa = (const float*)d_in[10];
    const float* Wt = (const float*)d_in[11];
    const float* Wb = (const float*)d_in[12];
    const float* bt = (const float*)d_in[13];
    const float* Wfc = (const float*)d_in[14];
    const float* bfc = (const float*)d_in[15];
    const float* Wsc = (const float*)d_in[16];
    const float* bsc = (const float*)d_in[17];
    float* out = (float*)d_out;

    const int N = in_sizes[0] / 96;
    const int E = in_sizes[2] / 2;
    const int NBUK = (N + BW - 1) / BW;  // buckets (must be <= 1024)
    int cap = ((2 * (E / NBUK)) + 255) & ~255;  // bucket capacity: 2x average, safe
    if (cap < 256) cap = 256;

    char* ws = (char*)d_ws;
    size_t o = 0;
    auto alloc = [&](size_t bytes) {
        void* p = ws + o;
        o += (bytes + 255) & ~(size_t)255;
        return p;
    };
    int* bcur = (int*)alloc((size_t)2 * 1024 * 4);
    int* soff0 = (int*)alloc((size_t)N * 4);
    int* soff1 = (int*)alloc((size_t)N * 4);
    int* eoff0 = (int*)alloc((size_t)N * 4);
    int* eoff1 = (int*)alloc((size_t)N * 4);
    u16* col0 = (u16*)alloc((size_t)NBUK * cap * 2);
    u16* col1 = (u16*)alloc((size_t)NBUK * cap * 2);
    int* ebuf0 = (int*)alloc((size_t)NBUK * cap * 4);
    int* ebuf1 = (int*)alloc((size_t)NBUK * cap * 4);
    float* dinv0 = (float*)alloc((size_t)N * 4);
    float* dinv1 = (float*)alloc((size_t)N * 4);
    u16* hwbA0 = (u16*)alloc((size_t)N * 64 * 2);  // layer-1 payload
    u16* hwbA1 = (u16*)alloc((size_t)N * 64 * 2);
    u16* hwbB0 = (u16*)alloc((size_t)N * 32 * 2);  // layer-2 payload
    u16* hwbB1 = (u16*)alloc((size_t)N * 32 * 2);
    u16* hwbC0 = (u16*)alloc((size_t)N * 16 * 2);  // layer-3 payload
    u16* hwbC1 = (u16*)alloc((size_t)N * 16 * 2);
    u16* H30 = (u16*)alloc((size_t)N * 16 * 2);  // H3 bf16 (pool input)
    u16* H31 = (u16*)alloc((size_t)N * 16 * 2);

    const int gB2 = (E + 4095) / 4096;
    const int g16 = ((size_t)N * 16 + TPB - 1) / TPB;  // aggs: 16 threads/node
    const int gSwz = 8 * ((g16 + 3) / 4);              // 4-XCD-per-graph swizzled grid
    const int gMM = (N + 63) / 64;
    const int gPool = 256;

    float* pcol = (float*)alloc((size_t)2 * g16 * 16 * 4);
    float* cvecArr = (float*)alloc(32 * 4);
    float* ppool = (float*)alloc((size_t)2 * gPool * 16 * 4);

    hipMemsetAsync(bcur, 0, (size_t)2 * 1024 * 4, stream);

    // capacity-bucket CSR build: scatter -> per-bucket finalize (no count/scan passes)
    bucket_scatter_kernel<<<dim3(gB2, 2), TPB, 0, stream>>>(edges1, edges2, E, bcur,
                                                            ebuf0, ebuf1, NBUK, cap);
    bucket_csr_kernel<<<dim3(NBUK, 2), TPB, 0, stream>>>(ebuf0, ebuf1, bcur, N, cap,
                                                         soff0, soff1, eoff0, eoff1,
                                                         dinv0, dinv1, col0, col1);

    // layer 1 matmul (MFMA 96->64)
    matmul_kernel<96, 64><<<dim3(gMM, 2), TPB, 0, stream>>>(X1, X2, W1, dinv0, dinv1,
                                                            hwbA0, hwbA1, N);
    // layer-1 agg + fused layer-2 MFMA matmul (64 -> H1 -> @W2 -> 32 bf16)
    agg_mm_kernel<64, 1, 32><<<gSwz, TPB, 0, stream>>>(
        hwbA0, hwbA1, soff0, soff1, eoff0, eoff1, col0, col1, dinv0, dinv1, b1, W2,
        hwbB0, hwbB1, N, g16);
    // layer-2 agg + fused layer-3 MFMA matmul (32 -> H2 -> @W3 -> 16 bf16)
    agg_mm_kernel<32, 2, 16><<<gSwz, TPB, 0, stream>>>(
        hwbB0, hwbB1, soff0, soff1, eoff0, eoff1, col0, col1, dinv0, dinv1, b2, W3,
        hwbC0, hwbC1, N, g16);
    // layer-3 agg (writes H3 bf16 + colsum partials)
    agg16_kernel<<<gSwz, TPB, 0, stream>>>(
        hwbC0, hwbC1, soff0, soff1, eoff0, eoff1, col0, col1, dinv0, dinv1, b3,
        H30, H31, pcol, N, g16);

    // attention pooling + scoring
    cvec_kernel<<<2, TPB, 0, stream>>>(pcol, g16, 1.0f / (float)N, Wa, cvecArr);
    pool_kernel<<<dim3(gPool, 2), TPB, 0, stream>>>(H30, H31, N, cvecArr, ppool);
    final_kernel<<<1, 256, 0, stream>>>(ppool, gPool, Wt, Wb, bt, Wfc, bfc, Wsc, bsc, out);
}